// Round 9
// baseline (1031.082 us; speedup 1.0000x reference)
//
#include <hip/hip_runtime.h>

// Conformer block — bf16 MFMA everywhere; round 15 resubmit (container infra
// failure last round; kernel unchanged, re-audited for hangs/OOB — none):
// * attn: K/V LDS staging REMOVED (they are L2-resident: 128KB per (b,h),
//   re-read by 16 XCD-pinned blocks). QK/PV fragments load straight from
//   global as dwordx4 (16B/lane, same contiguity the staging used). No
//   double-buffer, no barriers at all (SP rows are wave-disjoint). LDS
//   41984 -> 9216 B => occupancy ceiling 3 -> 6-8 blocks/CU.
// * everything else identical to r14 (GEMM BK=64 + LDS-bounce epilogue,
//   merged QKV, fused GLU+dwconv, 2-row LN).
// B=16 N=1024 DIM=512 H=8 DH=64 FF=2048 CIN=1024 K=31 MAXPOS=512. BN=16384.

#define BN 16384

typedef unsigned short u16;
typedef __attribute__((ext_vector_type(8))) __bf16 bf16x8;
typedef __attribute__((ext_vector_type(4))) float f32x4;
typedef __attribute__((ext_vector_type(8))) unsigned short u16x8;

__device__ __forceinline__ float sigf(float x) { return 1.f / (1.f + __expf(-x)); }
__device__ __forceinline__ u16 f2bf(float f) {
  unsigned int u = __float_as_uint(f);
  u += 0x7FFF + ((u >> 16) & 1);
  return (u16)(u >> 16);
}
// native cast: single v_cvt instruction, same RTNE rounding
__device__ __forceinline__ u16 f2bfn(float f) {
  const __bf16 h = (__bf16)f;
  return __builtin_bit_cast(u16, h);
}
__device__ __forceinline__ float bf2f(u16 u) {
  return __uint_as_float(((unsigned int)u) << 16);
}
__device__ __forceinline__ void gl_lds16(const void* g, void* lds) {
  __builtin_amdgcn_global_load_lds(
      (const __attribute__((address_space(1))) unsigned int*)g,
      (__attribute__((address_space(3))) unsigned int*)lds, 16, 0, 0);
}

// ---------------------------------------------------------------- layernorm
// 2 rows per block; 128 threads/row, float4 (16B) loads.
__global__ __launch_bounds__(256) void ln_kernel(const float* __restrict__ in,
    const float* __restrict__ g, const float* __restrict__ b,
    u16* outb, float* outf) {
  const int t = threadIdx.x;
  const int row = blockIdx.x * 2 + (t >> 7);
  const int tl = t & 127;
  const float4 v = ((const float4*)(in + (size_t)row * 512))[tl];
  float s = v.x + v.y + v.z + v.w;
  float sq = v.x * v.x + v.y * v.y + v.z * v.z + v.w * v.w;
#pragma unroll
  for (int o = 32; o > 0; o >>= 1) {
    s += __shfl_down(s, o);
    sq += __shfl_down(sq, o);
  }
  __shared__ float ss[4], ssq[4];
  if ((t & 63) == 0) { ss[t >> 6] = s; ssq[t >> 6] = sq; }
  __syncthreads();
  const int base = (t >> 7) * 2;
  s = ss[base] + ss[base + 1];
  sq = ssq[base] + ssq[base + 1];
  const float mu = s * (1.f / 512.f);
  const float var = fmaxf(sq * (1.f / 512.f) - mu * mu, 0.f);
  const float rstd = rsqrtf(var + 1e-5f);
  const float4 gg = ((const float4*)g)[tl];
  const float4 bb = ((const float4*)b)[tl];
  float o0 = (v.x - mu) * rstd * gg.x + bb.x;
  float o1 = (v.y - mu) * rstd * gg.y + bb.y;
  float o2 = (v.z - mu) * rstd * gg.z + bb.z;
  float o3 = (v.w - mu) * rstd * gg.w + bb.w;
  if (outf) {
    float4 o4 = {o0, o1, o2, o3};
    ((float4*)(outf + (size_t)row * 512))[tl] = o4;
  } else {
    ushort4 u4 = {f2bf(o0), f2bf(o1), f2bf(o2), f2bf(o3)};
    ((ushort4*)(outb + (size_t)row * 512))[tl] = u4;
  }
}

// ---------------------------------------------------------------- weight prep
__global__ __launch_bounds__(256) void wtrans(const float* __restrict__ W,
                                              u16* __restrict__ WT, int K, int N) {
  const int n0 = blockIdx.x * 32, k0 = blockIdx.y * 32;
  const int t = threadIdx.x;
  const int tx = t & 31, ty = t >> 5;
  __shared__ float T[32][33];
#pragma unroll
  for (int i = 0; i < 4; ++i)
    T[tx][ty + 8 * i] = W[(size_t)(k0 + ty + 8 * i) * N + n0 + tx];
  __syncthreads();
#pragma unroll
  for (int i = 0; i < 4; ++i)
    WT[(size_t)(n0 + ty + 8 * i) * K + k0 + tx] = f2bf(T[ty + 8 * i][tx]);
}

__global__ __launch_bounds__(256) void cvt_bf16(const float* __restrict__ in,
                                                u16* __restrict__ out, int n) {
  const int i = blockIdx.x * 256 + threadIdx.x;
  if (i < n) out[i] = f2bf(in[i]);
}

// ---------------------------------------------------------------- bf16 MFMA gemm
// C[M x N] = epi(A[M x K] @ WT[N x K]^T); C row stride = ldc. BK=64.
// LDS tiles 128x64 bf16, 16B-chunk XOR swizzle (see r11). 2 barriers/K-step.
// Epilogue: bf16-C blocks bounce the C-tile through Ast+Bst (rows 0-63 in
// Ast, 64-127 in Bst; stride 128) and store u16x8 (dwordx4) coalesced.
// alpha applied to cols < qn only. VTout: cols >= vt0 transposed into VT.
// XCD swizzle: contiguous m-band per XCD, column-fast.
__global__ __launch_bounds__(256) void gemm_bf16(const u16* __restrict__ A,
    const u16* __restrict__ WT, const float* __restrict__ bias,
    const float* res, float* Cf, u16* Cb, u16* VTout, int K, int N, int ldc,
    float alpha, int act, int qn, int vt0) {
  __shared__ __align__(16) u16 Ast[128 * 64];
  __shared__ __align__(16) u16 Bst[128 * 64];
  const int t = threadIdx.x;
  int bx = blockIdx.x, by = blockIdx.y;
  {
    const int nx = gridDim.x;
    const int lin = bx + nx * by;
    const int xcd = lin & 7;
    const int s = lin >> 3;
    const int ny8 = gridDim.y >> 3;
    const int sy = s / nx;
    by = xcd * ny8 + sy;
    bx = s - sy * nx;
  }
  const int n0 = bx * 128;
  const int m0 = by * 128;
  const int w = t >> 6;
  const int lc = t & 15, lq = (t >> 4) & 3;
  const int wy = w >> 1, wx = w & 1;
  f32x4 acc[4][4];
#pragma unroll
  for (int i = 0; i < 4; ++i)
#pragma unroll
    for (int j = 0; j < 4; ++j)
#pragma unroll
      for (int r = 0; r < 4; ++r) acc[i][j][r] = 0.f;

  const int koff0 = (lq ^ (lc & 7)) * 8;        // kk=0 chunk offset
  const int koff1 = ((4 + lq) ^ (lc & 7)) * 8;  // kk=1 chunk offset

  for (int kt = 0; kt < K; kt += 64) {
#pragma unroll
    for (int s = 0; s < 4; ++s) {
      const int f = t + 256 * s;
      const int fr = f >> 3;
      const int fc = (f & 7) ^ (fr & 7);
      gl_lds16(&A[(size_t)(m0 + fr) * K + kt + fc * 8], &Ast[f * 8]);
      gl_lds16(&WT[(size_t)(n0 + fr) * K + kt + fc * 8], &Bst[f * 8]);
    }
    __syncthreads();
#pragma unroll
    for (int kk = 0; kk < 2; ++kk) {
      const int koff = kk ? koff1 : koff0;
      bf16x8 bfr[4];
#pragma unroll
      for (int j = 0; j < 4; ++j)
        bfr[j] = *(const bf16x8*)&Bst[(wx * 64 + j * 16 + lc) * 64 + koff];
#pragma unroll
      for (int i = 0; i < 4; ++i) {
        const bf16x8 af = *(const bf16x8*)&Ast[(wy * 64 + i * 16 + lc) * 64 + koff];
#pragma unroll
        for (int j = 0; j < 4; ++j)
          acc[i][j] = __builtin_amdgcn_mfma_f32_16x16x32_bf16(af, bfr[j], acc[i][j], 0, 0, 0);
      }
    }
    __syncthreads();
  }

  const bool vtblk = (VTout != nullptr) && (n0 >= vt0);
  if (Cb && !vtblk) {
    // ---- bf16 C via LDS bounce (res is always null on this path) ----
#pragma unroll
    for (int j = 0; j < 4; ++j) {
      const int coll = wx * 64 + j * 16 + lc;
      const float bj = bias ? bias[n0 + coll] : 0.f;
      const float al = ((n0 + coll) < qn) ? alpha : 1.f;
#pragma unroll
      for (int i = 0; i < 4; ++i) {
        const int rowl0 = wy * 64 + i * 16 + lq * 4;
#pragma unroll
        for (int r = 0; r < 4; ++r) {
          float v = acc[i][j][r] + bj;
          if (act) v = v * sigf(v);
          v *= al;
          const int rowl = rowl0 + r;
          u16* cl = (rowl < 64) ? &Ast[rowl * 128] : &Bst[(rowl - 64) * 128];
          cl[coll] = f2bfn(v);
        }
      }
    }
    __syncthreads();
#pragma unroll
    for (int vv = 0; vv < 8; ++vv) {
      const int e = t + 256 * vv;
      const int rowl = e >> 4;
      const int col = (e & 15) * 8;
      const u16* cl = (rowl < 64) ? &Ast[rowl * 128] : &Bst[(rowl - 64) * 128];
      const u16x8 val = *(const u16x8*)&cl[col];
      *(u16x8*)&Cb[(size_t)(m0 + rowl) * ldc + n0 + col] = val;
    }
    return;
  }

#pragma unroll
  for (int j = 0; j < 4; ++j) {
    const int col = n0 + wx * 64 + j * 16 + lc;
    const float bj = bias ? bias[col] : 0.f;
    const float al = (col < qn) ? alpha : 1.f;
    const bool vtc = vtblk && (col >= vt0);
#pragma unroll
    for (int i = 0; i < 4; ++i) {
      const int row0 = m0 + wy * 64 + i * 16 + lq * 4;
      float v4[4];
#pragma unroll
      for (int r = 0; r < 4; ++r) {
        float v = acc[i][j][r] + bj;
        if (act) v = v * sigf(v);
        v *= al;
        if (res) v += res[(size_t)(row0 + r) * ldc + col];
        v4[r] = v;
      }
      if (vtc) {
        const int cm = col - vt0;
        const int hh = cm >> 6, dd = cm & 63;
        const int bb = row0 >> 10, nl = row0 & 1023;
        ushort4 o4 = {f2bfn(v4[0]), f2bfn(v4[1]), f2bfn(v4[2]), f2bfn(v4[3])};
        *(ushort4*)&VTout[((size_t)((bb * 8 + hh) * 64 + dd)) * 1024 + nl] = o4;
      } else {
#pragma unroll
        for (int r = 0; r < 4; ++r) {
          const size_t off = (size_t)(row0 + r) * ldc + col;
          if (Cf) Cf[off] = v4[r];
          else Cb[off] = f2bfn(v4[r]);
        }
      }
    }
  }
}

// ---------------------------------------------------------------- flash attention (MFMA)
// q64 tile, 4 waves; merged in-place SP buffer; Q pre-scaled by 0.125*log2e;
// streaming softmax (bounded scores), deferred denominator reduce.
// Round 15: NO K/V LDS staging — K and V are L2-resident (128KB per (b,h),
// 16 XCD-pinned blocks re-read them); QK/PV fragments are 16B-contiguous per
// lane in global layout and load directly as dwordx4. No barriers anywhere
// (SP rows are wave-disjoint). LDS = SP only (9216 B).
// XCD swizzle: all 16 q-tiles of one (b,h) on one XCD (lin&127 = hb).
__global__ __launch_bounds__(256) void attn_mfma(const u16* __restrict__ QKV,
    const u16* __restrict__ Vt, const u16* __restrict__ Rb, u16* __restrict__ O) {
  const int lin = blockIdx.x;
  const int hb = lin & 127;            // (b,h) group
  const int n0 = (lin >> 7) * 64;      // q-tile
  const int h = hb & 7, b = hb >> 3;
  const int t = threadIdx.x;
  const int w = t >> 6;
  const int lc = t & 15, lq = (t >> 4) & 3;

  __shared__ __align__(16) u16 SP[64 * 72];   // pos scatter, then exp(S) in place

  bf16x8 qf[2];
  {
    const size_t qrow = (size_t)(b * 1024 + n0 + w * 16 + lc) * 1536 + h * 64;
    qf[0] = *(const bf16x8*)&QKV[qrow + lq * 8];
    qf[1] = *(const bf16x8*)&QKV[qrow + 32 + lq * 8];
  }

  // per-lane fragment bases (16B contiguous per lane):
  // K frag(j,ks)  at Kg + (j0 + j*16)*1536          (+ ks*32)
  // V frag(dt,ks) at Vg + dt*16*1024 + j0           (+ ks*32)
  const u16* Kg = QKV + (size_t)b * 1024 * 1536 + 512 + h * 64 + (size_t)lc * 1536 + lq * 8;
  const u16* Vg = Vt + (size_t)(b * 8 + h) * 64 * 1024 + (size_t)lc * 1024 + lq * 8;

  float l_r[4] = {0.f, 0.f, 0.f, 0.f};
  f32x4 o[4];
#pragma unroll
  for (int dt = 0; dt < 4; ++dt)
#pragma unroll
    for (int r = 0; r < 4; ++r) o[dt][r] = 0.f;

  for (int jt = 0; jt < 16; ++jt) {
    const int j0 = jt * 64;

    f32x4 qk[4], pa[5];
#pragma unroll
    for (int j = 0; j < 4; ++j)
#pragma unroll
      for (int r = 0; r < 4; ++r) qk[j][r] = 0.f;
#pragma unroll
    for (int rtl = 0; rtl < 5; ++rtl)
#pragma unroll
      for (int r = 0; r < 4; ++r) pa[rtl][r] = 0.f;

    // rel row pointers: clamp once per rtl (not per ks)
    const int base = n0 - j0 - 63;
    const u16* rp[5];
#pragma unroll
    for (int rtl = 0; rtl < 5; ++rtl) {
      int p = base + (w + rtl) * 16 + lc;
      p = (p < -512 ? -512 : (p > 512 ? 512 : p)) + 512;
      rp[rtl] = Rb + (size_t)p * 64 + lq * 8;
    }

#pragma unroll
    for (int ks = 0; ks < 2; ++ks) {
      bf16x8 rfr[5];
#pragma unroll
      for (int rtl = 0; rtl < 5; ++rtl)
        rfr[rtl] = *(const bf16x8*)&rp[rtl][ks * 32];
#pragma unroll
      for (int j = 0; j < 4; ++j) {
        const bf16x8 kf =
            *(const bf16x8*)&Kg[(size_t)(j0 + j * 16) * 1536 + ks * 32];
        qk[j] = __builtin_amdgcn_mfma_f32_16x16x32_bf16(qf[ks], kf, qk[j], 0, 0, 0);
      }
#pragma unroll
      for (int rtl = 0; rtl < 5; ++rtl)
        pa[rtl] = __builtin_amdgcn_mfma_f32_16x16x32_bf16(qf[ks], rfr[rtl], pa[rtl], 0, 0, 0);
    }

    // skewed scatter: P[qr][didx] -> SP[qr][jc], jc = qr - didx + 63 (wave-local)
#pragma unroll
    for (int rtl = 0; rtl < 5; ++rtl) {
      const int didx = (w + rtl) * 16 + lc;
#pragma unroll
      for (int r = 0; r < 4; ++r) {
        const int qr = w * 16 + lq * 4 + r;
        const int jc = qr - didx + 63;
        if ((unsigned)jc < 64u) SP[qr * 72 + jc] = f2bfn(pa[rtl][r]);
      }
    }

    // streaming softmax in place
#pragma unroll
    for (int r = 0; r < 4; ++r) {
      const int qr = w * 16 + lq * 4 + r;
#pragma unroll
      for (int ti = 0; ti < 4; ++ti) {
        const int a = qr * 72 + ti * 16 + lc;
        const float e = exp2f(qk[ti][r] + bf2f(SP[a]));
        SP[a] = f2bfn(e);
        l_r[r] += e;
      }
    }

    // PV (V fragments direct from global; L2-hit)
#pragma unroll
    for (int ks = 0; ks < 2; ++ks) {
      const bf16x8 af = *(const bf16x8*)&SP[(w * 16 + lc) * 72 + ks * 32 + lq * 8];
#pragma unroll
      for (int dt = 0; dt < 4; ++dt) {
        const bf16x8 vf =
            *(const bf16x8*)&Vg[(size_t)(dt * 16) * 1024 + j0 + ks * 32];
        o[dt] = __builtin_amdgcn_mfma_f32_16x16x32_bf16(af, vf, o[dt], 0, 0, 0);
      }
    }
  }

#pragma unroll
  for (int r = 0; r < 4; ++r) {
#pragma unroll
    for (int msk = 1; msk < 16; msk <<= 1) l_r[r] += __shfl_xor(l_r[r], msk);
  }

#pragma unroll
  for (int r = 0; r < 4; ++r) {
    const float inv = 1.f / l_r[r];
    const size_t row = (size_t)(b * 1024 + n0 + w * 16 + lq * 4 + r);
#pragma unroll
    for (int dt = 0; dt < 4; ++dt)
      O[row * 512 + h * 64 + dt * 16 + lc] = f2bfn(o[dt][r] * inv);
  }
}

// ---------------------------------------------------------------- depthwise conv (GLU fused)
// in = HID (2048 cols): a = in[.., c], g = in[.., 1024+c]; h = a*sig(g)
// computed in the hs-fill loop (glu kernel + GLUB round-trip eliminated).
__global__ __launch_bounds__(256) void dwconv_kernel(const u16* __restrict__ in,
    const float* __restrict__ w, const float* __restrict__ bias,
    u16* __restrict__ out) {
  const int n0 = blockIdx.x * 64;
  const int c0 = blockIdx.y * 64;
  const int b = blockIdx.z;
  const int t = threadIdx.x;
  __shared__ float hs[94][64];
  __shared__ float wsh[31][64];
  const int c = t & 63;
  const int g = t >> 6;
  for (int r = g; r < 94; r += 4) {
    const int n = n0 - 30 + r;
    float v = 0.f;
    if (n >= 0) {
      const size_t rowb = (size_t)(b * 1024 + n) * 2048;
      const float a = bf2f(in[rowb + c0 + c]);
      const float gg = bf2f(in[rowb + 1024 + c0 + c]);
      v = a * sigf(gg);
    }
    hs[r][c] = v;
  }
  for (int idx = t; idx < 31 * 64; idx += 256) {
    const int tap = idx >> 6, cc = idx & 63;
    wsh[tap][cc] = w[(size_t)(c0 + cc) * 31 + tap];
  }
  __syncthreads();
  float wr[31];
#pragma unroll
  for (int k = 0; k < 31; ++k) wr[k] = wsh[k][c];
  const float bsv = bias[c0 + c];
  float win[46];
  const int rbase = g * 16;
#pragma unroll
  for (int k = 0; k < 46; ++k) win[k] = hs[rbase + k][c];
#pragma unroll
  for (int i = 0; i < 16; ++i) {
    float acc = bsv;
#pragma unroll
    for (int k = 0; k < 31; ++k) acc += wr[k] * win[i + k];
    acc = acc * sigf(acc);
    out[(size_t)(b * 1024 + n0 + rbase + i) * 1024 + c0 + c] = f2bfn(acc);
  }
}

// ---------------------------------------------------------------- launch
extern "C" void kernel_launch(void* const* d_in, const int* in_sizes, int n_in,
                              void* d_out, int out_size, void* d_ws, size_t ws_size,
                              hipStream_t stream) {
  const float* x        = (const float*)d_in[0];
  const float* ff1_ln_g = (const float*)d_in[1];
  const float* ff1_ln_b = (const float*)d_in[2];
  const float* ff1_w1   = (const float*)d_in[3];
  const float* ff1_b1   = (const float*)d_in[4];
  const float* ff1_w2   = (const float*)d_in[5];
  const float* ff1_b2   = (const float*)d_in[6];
  const float* attn_ln_g= (const float*)d_in[7];
  const float* attn_ln_b= (const float*)d_in[8];
  const float* wq       = (const float*)d_in[9];
  const float* wkv      = (const float*)d_in[10];
  const float* wo       = (const float*)d_in[11];
  const float* bo       = (const float*)d_in[12];
  const float* rel_emb  = (const float*)d_in[13];
  const float* conv_ln_g= (const float*)d_in[14];
  const float* conv_ln_b= (const float*)d_in[15];
  const float* conv1_w  = (const float*)d_in[16];
  const float* conv1_b  = (const float*)d_in[17];
  const float* dw_w     = (const float*)d_in[18];
  const float* dw_b     = (const float*)d_in[19];
  const float* conv2_w  = (const float*)d_in[20];
  const float* conv2_b  = (const float*)d_in[21];
  const float* ff2_ln_g = (const float*)d_in[22];
  const float* ff2_ln_b = (const float*)d_in[23];
  const float* ff2_w1   = (const float*)d_in[24];
  const float* ff2_b1   = (const float*)d_in[25];
  const float* ff2_w2   = (const float*)d_in[26];
  const float* ff2_b2   = (const float*)d_in[27];
  const float* post_ln_g= (const float*)d_in[28];
  const float* post_ln_b= (const float*)d_in[29];

  float* XRES = (float*)d_out;
  u16* ws = (u16*)d_ws;
  u16* LNB  = ws;                                // BN*512
  u16* HID  = LNB + (size_t)BN * 512;            // BN*2048
  u16* QKVB = HID + (size_t)BN * 2048;           // BN*1536
  u16* VT   = QKVB + (size_t)BN * 1536;          // 8192*1024
  u16* DWB  = QKVB;                              // alias (QKV dead after attn)
  u16* WTp = VT + (size_t)8192 * 1024;
  u16* wt_ff1w1 = WTp;                 WTp += (size_t)2048 * 512;
  u16* wt_ff1w2 = WTp;                 WTp += (size_t)512 * 2048;
  u16* wt_qkv   = WTp;                 WTp += (size_t)1536 * 512;
  u16* wt_wo    = WTp;                 WTp += (size_t)512 * 512;
  u16* wt_conv1 = WTp;                 WTp += (size_t)2048 * 512;
  u16* wt_conv2 = WTp;                 WTp += (size_t)512 * 1024;
  u16* wt_ff2w1 = WTp;                 WTp += (size_t)2048 * 512;
  u16* wt_ff2w2 = WTp;                 WTp += (size_t)512 * 2048;
  u16* RELB     = WTp;

  const dim3 blk(256);
  const float SC = 0.125f * 1.44269504f;  // folded into Q projection

  // weight prep
  wtrans<<<dim3(64, 16), blk, 0, stream>>>(ff1_w1, wt_ff1w1, 512, 2048);
  wtrans<<<dim3(16, 64), blk, 0, stream>>>(ff1_w2, wt_ff1w2, 2048, 512);
  wtrans<<<dim3(16, 16), blk, 0, stream>>>(wq, wt_qkv, 512, 512);
  wtrans<<<dim3(32, 16), blk, 0, stream>>>(wkv, wt_qkv + (size_t)512 * 512, 512, 1024);
  wtrans<<<dim3(16, 16), blk, 0, stream>>>(wo, wt_wo, 512, 512);
  wtrans<<<dim3(64, 16), blk, 0, stream>>>(conv1_w, wt_conv1, 512, 2048);
  wtrans<<<dim3(16, 32), blk, 0, stream>>>(conv2_w, wt_conv2, 1024, 512);
  wtrans<<<dim3(64, 16), blk, 0, stream>>>(ff2_w1, wt_ff2w1, 512, 2048);
  wtrans<<<dim3(16, 64), blk, 0, stream>>>(ff2_w2, wt_ff2w2, 2048, 512);
  cvt_bf16<<<257, blk, 0, stream>>>(rel_emb, RELB, 1025 * 64);

  // --- FF1 (half-step)
  ln_kernel<<<BN / 2, blk, 0, stream>>>(x, ff1_ln_g, ff1_ln_b, LNB, nullptr);
  gemm_bf16<<<dim3(16, 128), blk, 0, stream>>>(LNB, wt_ff1w1, ff1_b1, nullptr,
                                               nullptr, HID, nullptr, 512, 2048, 2048, 1.f, 1, 2048, 0);
  gemm_bf16<<<dim3(4, 128), blk, 0, stream>>>(HID, wt_ff1w2, ff1_b2, x,
                                              XRES, nullptr, nullptr, 2048, 512, 512, 0.5f, 0, 512, 0);

  // --- attention (merged QKV projection: Q cols scaled by SC, V cols >=1024
  //     written transposed into VT; K row-major)
  ln_kernel<<<BN / 2, blk, 0, stream>>>(XRES, attn_ln_g, attn_ln_b, LNB, nullptr);
  gemm_bf16<<<dim3(12, 128), blk, 0, stream>>>(LNB, wt_qkv, nullptr, nullptr,
                                               nullptr, QKVB, VT, 512, 1536, 1536, SC, 0, 512, 1024);
  attn_mfma<<<dim3(2048), blk, 0, stream>>>(QKVB, VT, RELB, LNB);
  gemm_bf16<<<dim3(4, 128), blk, 0, stream>>>(LNB, wt_wo, bo, XRES,
                                              XRES, nullptr, nullptr, 512, 512, 512, 1.f, 0, 512, 0);

  // --- conv module (GLU fused into dwconv; HID -> DWB directly)
  ln_kernel<<<BN / 2, blk, 0, stream>>>(XRES, conv_ln_g, conv_ln_b, LNB, nullptr);
  gemm_bf16<<<dim3(16, 128), blk, 0, stream>>>(LNB, wt_conv1, conv1_b, nullptr,
                                               nullptr, HID, nullptr, 512, 2048, 2048, 1.f, 0, 2048, 0);
  dwconv_kernel<<<dim3(16, 16, 16), blk, 0, stream>>>(HID, dw_w, dw_b, DWB);
  gemm_bf16<<<dim3(4, 128), blk, 0, stream>>>(DWB, wt_conv2, conv2_b, XRES,
                                              XRES, nullptr, nullptr, 1024, 512, 512, 1.f, 0, 512, 0);

  // --- FF2 (half-step)
  ln_kernel<<<BN / 2, blk, 0, stream>>>(XRES, ff2_ln_g, ff2_ln_b, LNB, nullptr);
  gemm_bf16<<<dim3(16, 128), blk, 0, stream>>>(LNB, wt_ff2w1, ff2_b1, nullptr,
                                               nullptr, HID, nullptr, 512, 2048, 2048, 1.f, 1, 2048, 0);
  gemm_bf16<<<dim3(4, 128), blk, 0, stream>>>(HID, wt_ff2w2, ff2_b2, XRES,
                                              XRES, nullptr, nullptr, 2048, 512, 512, 0.5f, 0, 512, 0);

  // --- final layernorm
  ln_kernel<<<BN / 2, blk, 0, stream>>>(XRES, post_ln_g, post_ln_b, nullptr, XRES);
}

// Round 10
// 862.660 us; speedup vs baseline: 1.1952x; 1.1952x over previous
//
#include <hip/hip_runtime.h>

// Conformer block — bf16 MFMA everywhere; round 16 (base = r14, 862us):
// * attn REVERTED to r14 staged version (r15's direct-global fragment loads
//   were 16-line gathers: MfmaUtil 6%, 366us. Staging = coalescing.)
// * NEW gemm256: 256x256 tile, 8 waves (512 thr), BK=64, single-barrier
//   2-phase schedule (stage next tile BEFORE compute; one __syncthreads per
//   K-step drains prefetch AFTER 64 MFMA/wave of cover) — the guide's
//   minimum-2-phase recipe, measured 660-680 TF at this geometry. LDS 128KB
//   (2 dbuf x (A+B) 256x64), 8-chunk XOR swizzle as in r11. C bounced
//   through the freed 128KB LDS, stored as dwordx4. Used for the three wide
//   N=2048 K=512 GEMMs (ff1w1, conv1, ff2w1).
// * everything else identical to r14.
// B=16 N=1024 DIM=512 H=8 DH=64 FF=2048 CIN=1024 K=31 MAXPOS=512. BN=16384.

#define BN 16384

typedef unsigned short u16;
typedef __attribute__((ext_vector_type(8))) __bf16 bf16x8;
typedef __attribute__((ext_vector_type(4))) float f32x4;
typedef __attribute__((ext_vector_type(8))) unsigned short u16x8;

__device__ __forceinline__ float sigf(float x) { return 1.f / (1.f + __expf(-x)); }
__device__ __forceinline__ u16 f2bf(float f) {
  unsigned int u = __float_as_uint(f);
  u += 0x7FFF + ((u >> 16) & 1);
  return (u16)(u >> 16);
}
__device__ __forceinline__ u16 f2bfn(float f) {
  const __bf16 h = (__bf16)f;
  return __builtin_bit_cast(u16, h);
}
__device__ __forceinline__ float bf2f(u16 u) {
  return __uint_as_float(((unsigned int)u) << 16);
}
__device__ __forceinline__ void gl_lds16(const void* g, void* lds) {
  __builtin_amdgcn_global_load_lds(
      (const __attribute__((address_space(1))) unsigned int*)g,
      (__attribute__((address_space(3))) unsigned int*)lds, 16, 0, 0);
}

// ---------------------------------------------------------------- layernorm
// 2 rows per block; 128 threads/row, float4 (16B) loads.
__global__ __launch_bounds__(256) void ln_kernel(const float* __restrict__ in,
    const float* __restrict__ g, const float* __restrict__ b,
    u16* outb, float* outf) {
  const int t = threadIdx.x;
  const int row = blockIdx.x * 2 + (t >> 7);
  const int tl = t & 127;
  const float4 v = ((const float4*)(in + (size_t)row * 512))[tl];
  float s = v.x + v.y + v.z + v.w;
  float sq = v.x * v.x + v.y * v.y + v.z * v.z + v.w * v.w;
#pragma unroll
  for (int o = 32; o > 0; o >>= 1) {
    s += __shfl_down(s, o);
    sq += __shfl_down(sq, o);
  }
  __shared__ float ss[4], ssq[4];
  if ((t & 63) == 0) { ss[t >> 6] = s; ssq[t >> 6] = sq; }
  __syncthreads();
  const int base = (t >> 7) * 2;
  s = ss[base] + ss[base + 1];
  sq = ssq[base] + ssq[base + 1];
  const float mu = s * (1.f / 512.f);
  const float var = fmaxf(sq * (1.f / 512.f) - mu * mu, 0.f);
  const float rstd = rsqrtf(var + 1e-5f);
  const float4 gg = ((const float4*)g)[tl];
  const float4 bb = ((const float4*)b)[tl];
  float o0 = (v.x - mu) * rstd * gg.x + bb.x;
  float o1 = (v.y - mu) * rstd * gg.y + bb.y;
  float o2 = (v.z - mu) * rstd * gg.z + bb.z;
  float o3 = (v.w - mu) * rstd * gg.w + bb.w;
  if (outf) {
    float4 o4 = {o0, o1, o2, o3};
    ((float4*)(outf + (size_t)row * 512))[tl] = o4;
  } else {
    ushort4 u4 = {f2bf(o0), f2bf(o1), f2bf(o2), f2bf(o3)};
    ((ushort4*)(outb + (size_t)row * 512))[tl] = u4;
  }
}

// ---------------------------------------------------------------- weight prep
__global__ __launch_bounds__(256) void wtrans(const float* __restrict__ W,
                                              u16* __restrict__ WT, int K, int N) {
  const int n0 = blockIdx.x * 32, k0 = blockIdx.y * 32;
  const int t = threadIdx.x;
  const int tx = t & 31, ty = t >> 5;
  __shared__ float T[32][33];
#pragma unroll
  for (int i = 0; i < 4; ++i)
    T[tx][ty + 8 * i] = W[(size_t)(k0 + ty + 8 * i) * N + n0 + tx];
  __syncthreads();
#pragma unroll
  for (int i = 0; i < 4; ++i)
    WT[(size_t)(n0 + ty + 8 * i) * K + k0 + tx] = f2bf(T[ty + 8 * i][tx]);
}

__global__ __launch_bounds__(256) void cvt_bf16(const float* __restrict__ in,
                                                u16* __restrict__ out, int n) {
  const int i = blockIdx.x * 256 + threadIdx.x;
  if (i < n) out[i] = f2bf(in[i]);
}

// ---------------------------------------------------------------- 256^2 2-phase GEMM
// C[M x N] = epi(A[M x K] @ WT[N x K]^T), bf16 C, bias + optional swish.
// 256x256 tile, 8 waves (2M x 4N), BK=64, double-buffered 128KB LDS,
// ONE __syncthreads per K-step: stage(next)->compute(cur)->sync. The sync's
// vmcnt(0) drain lands after 64 MFMA/wave of cover. 16B-chunk XOR swizzle
// (8 chunks/row) identical to the proven r11 mapping. Epilogue bounces the
// 256x256 C tile through the freed 128KB LDS, stores u16x8.
// Requires: M%256==0, N%256==0, K%128==0. XCD swizzle: m-band per XCD.
__global__ __launch_bounds__(512) void gemm256(const u16* __restrict__ A,
    const u16* __restrict__ WT, const float* __restrict__ bias,
    u16* __restrict__ Cb, int K, int ldc, int act) {
  __shared__ __align__(16) u16 LDSB[65536];   // 128 KB
  u16* const As0 = LDSB;                      // 256x64
  u16* const As1 = LDSB + 16384;
  u16* const Bs0 = LDSB + 32768;
  u16* const Bs1 = LDSB + 49152;
  const int t = threadIdx.x;
  int bx = blockIdx.x, by = blockIdx.y;
  {
    const int nx = gridDim.x;
    const int lin = bx + nx * by;
    const int xcd = lin & 7;
    const int s = lin >> 3;
    const int ny8 = gridDim.y >> 3;
    const int sy = s / nx;
    by = xcd * ny8 + sy;
    bx = s - sy * nx;
  }
  const int n0 = bx * 256;
  const int m0 = by * 256;
  const int w = t >> 6;
  const int wr = w >> 2, wc = w & 3;          // 2M x 4N wave grid
  const int lc = t & 15, lq = (t >> 4) & 3;

  f32x4 acc[8][4];
#pragma unroll
  for (int i = 0; i < 8; ++i)
#pragma unroll
    for (int j = 0; j < 4; ++j)
#pragma unroll
      for (int r = 0; r < 4; ++r) acc[i][j][r] = 0.f;

  // staging geometry: f = t + 512*s (s=0..3), row = f>>3 (0..255),
  // chunk = f&7; swizzled source chunk = (f&7)^(row&7); dest linear f*16B.
  int sfr[4], sfc[4];
#pragma unroll
  for (int s = 0; s < 4; ++s) {
    const int f = t + 512 * s;
    sfr[s] = f >> 3;
    sfc[s] = ((f & 7) ^ (sfr[s] & 7)) * 8;
  }

  auto STAGE = [&](u16* Ad, u16* Bd, int kt) {
#pragma unroll
    for (int s = 0; s < 4; ++s) {
      gl_lds16(&A[(size_t)(m0 + sfr[s]) * K + kt + sfc[s]], &Ad[(t + 512 * s) * 8]);
      gl_lds16(&WT[(size_t)(n0 + sfr[s]) * K + kt + sfc[s]], &Bd[(t + 512 * s) * 8]);
    }
  };

  auto COMPUTE = [&](const u16* Asrc, const u16* Bsrc) {
#pragma unroll
    for (int kk = 0; kk < 2; ++kk) {
      const int koff = ((kk * 4 + lq) ^ (lc & 7)) * 8;
      bf16x8 bfr[4];
#pragma unroll
      for (int j = 0; j < 4; ++j)
        bfr[j] = *(const bf16x8*)&Bsrc[(wc * 64 + j * 16 + lc) * 64 + koff];
#pragma unroll
      for (int i = 0; i < 8; ++i) {
        const bf16x8 af = *(const bf16x8*)&Asrc[(wr * 128 + i * 16 + lc) * 64 + koff];
#pragma unroll
        for (int j = 0; j < 4; ++j)
          acc[i][j] = __builtin_amdgcn_mfma_f32_16x16x32_bf16(af, bfr[j], acc[i][j], 0, 0, 0);
      }
    }
  };

  // prologue: tile 0 -> buf0
  STAGE(As0, Bs0, 0);
  __syncthreads();                    // vmcnt(0): tile 0 landed

  for (int kt2 = 0; kt2 < K; kt2 += 128) {
    STAGE(As1, Bs1, kt2 + 64);        // prefetch odd tile (always valid: K%128==0)
    COMPUTE(As0, Bs0);                // 64 MFMA/wave cover the prefetch
    __syncthreads();                  // drain + publish buf1; buf0 free
    if (kt2 + 128 < K) STAGE(As0, Bs0, kt2 + 128);
    COMPUTE(As1, Bs1);
    __syncthreads();
  }

  // epilogue: bounce C (256x256 bf16 = 128KB = whole LDS, now free)
#pragma unroll
  for (int j = 0; j < 4; ++j) {
    const int coll = wc * 64 + j * 16 + lc;
    const float bj = bias[n0 + coll];
#pragma unroll
    for (int i = 0; i < 8; ++i) {
      const int rowl0 = wr * 128 + i * 16 + lq * 4;
#pragma unroll
      for (int r = 0; r < 4; ++r) {
        float v = acc[i][j][r] + bj;
        if (act) v = v * sigf(v);
        LDSB[(rowl0 + r) * 256 + coll] = f2bfn(v);
      }
    }
  }
  __syncthreads();
#pragma unroll
  for (int vv = 0; vv < 16; ++vv) {
    const int e = t + 512 * vv;
    *(u16x8*)&Cb[(size_t)(m0 + (e >> 5)) * ldc + n0 + (e & 31) * 8] =
        *(const u16x8*)&LDSB[e * 8];
  }
}

// ---------------------------------------------------------------- bf16 MFMA gemm (128^2)
// C[M x N] = epi(A[M x K] @ WT[N x K]^T); C row stride = ldc. BK=64.
// LDS tiles 128x64 bf16, 16B-chunk XOR swizzle (see r11). 2 barriers/K-step.
// Epilogue: bf16-C blocks bounce the C-tile through Ast+Bst and store u16x8.
// alpha applied to cols < qn only. VTout: cols >= vt0 transposed into VT.
// XCD swizzle: contiguous m-band per XCD, column-fast.
__global__ __launch_bounds__(256) void gemm_bf16(const u16* __restrict__ A,
    const u16* __restrict__ WT, const float* __restrict__ bias,
    const float* res, float* Cf, u16* Cb, u16* VTout, int K, int N, int ldc,
    float alpha, int act, int qn, int vt0) {
  __shared__ __align__(16) u16 Ast[128 * 64];
  __shared__ __align__(16) u16 Bst[128 * 64];
  const int t = threadIdx.x;
  int bx = blockIdx.x, by = blockIdx.y;
  {
    const int nx = gridDim.x;
    const int lin = bx + nx * by;
    const int xcd = lin & 7;
    const int s = lin >> 3;
    const int ny8 = gridDim.y >> 3;
    const int sy = s / nx;
    by = xcd * ny8 + sy;
    bx = s - sy * nx;
  }
  const int n0 = bx * 128;
  const int m0 = by * 128;
  const int w = t >> 6;
  const int lc = t & 15, lq = (t >> 4) & 3;
  const int wy = w >> 1, wx = w & 1;
  f32x4 acc[4][4];
#pragma unroll
  for (int i = 0; i < 4; ++i)
#pragma unroll
    for (int j = 0; j < 4; ++j)
#pragma unroll
      for (int r = 0; r < 4; ++r) acc[i][j][r] = 0.f;

  const int koff0 = (lq ^ (lc & 7)) * 8;
  const int koff1 = ((4 + lq) ^ (lc & 7)) * 8;

  for (int kt = 0; kt < K; kt += 64) {
#pragma unroll
    for (int s = 0; s < 4; ++s) {
      const int f = t + 256 * s;
      const int fr = f >> 3;
      const int fc = (f & 7) ^ (fr & 7);
      gl_lds16(&A[(size_t)(m0 + fr) * K + kt + fc * 8], &Ast[f * 8]);
      gl_lds16(&WT[(size_t)(n0 + fr) * K + kt + fc * 8], &Bst[f * 8]);
    }
    __syncthreads();
#pragma unroll
    for (int kk = 0; kk < 2; ++kk) {
      const int koff = kk ? koff1 : koff0;
      bf16x8 bfr[4];
#pragma unroll
      for (int j = 0; j < 4; ++j)
        bfr[j] = *(const bf16x8*)&Bst[(wx * 64 + j * 16 + lc) * 64 + koff];
#pragma unroll
      for (int i = 0; i < 4; ++i) {
        const bf16x8 af = *(const bf16x8*)&Ast[(wy * 64 + i * 16 + lc) * 64 + koff];
#pragma unroll
        for (int j = 0; j < 4; ++j)
          acc[i][j] = __builtin_amdgcn_mfma_f32_16x16x32_bf16(af, bfr[j], acc[i][j], 0, 0, 0);
      }
    }
    __syncthreads();
  }

  const bool vtblk = (VTout != nullptr) && (n0 >= vt0);
  if (Cb && !vtblk) {
#pragma unroll
    for (int j = 0; j < 4; ++j) {
      const int coll = wx * 64 + j * 16 + lc;
      const float bj = bias ? bias[n0 + coll] : 0.f;
      const float al = ((n0 + coll) < qn) ? alpha : 1.f;
#pragma unroll
      for (int i = 0; i < 4; ++i) {
        const int rowl0 = wy * 64 + i * 16 + lq * 4;
#pragma unroll
        for (int r = 0; r < 4; ++r) {
          float v = acc[i][j][r] + bj;
          if (act) v = v * sigf(v);
          v *= al;
          const int rowl = rowl0 + r;
          u16* cl = (rowl < 64) ? &Ast[rowl * 128] : &Bst[(rowl - 64) * 128];
          cl[coll] = f2bfn(v);
        }
      }
    }
    __syncthreads();
#pragma unroll
    for (int vv = 0; vv < 8; ++vv) {
      const int e = t + 256 * vv;
      const int rowl = e >> 4;
      const int col = (e & 15) * 8;
      const u16* cl = (rowl < 64) ? &Ast[rowl * 128] : &Bst[(rowl - 64) * 128];
      const u16x8 val = *(const u16x8*)&cl[col];
      *(u16x8*)&Cb[(size_t)(m0 + rowl) * ldc + n0 + col] = val;
    }
    return;
  }

#pragma unroll
  for (int j = 0; j < 4; ++j) {
    const int col = n0 + wx * 64 + j * 16 + lc;
    const float bj = bias ? bias[col] : 0.f;
    const float al = (col < qn) ? alpha : 1.f;
    const bool vtc = vtblk && (col >= vt0);
#pragma unroll
    for (int i = 0; i < 4; ++i) {
      const int row0 = m0 + wy * 64 + i * 16 + lq * 4;
      float v4[4];
#pragma unroll
      for (int r = 0; r < 4; ++r) {
        float v = acc[i][j][r] + bj;
        if (act) v = v * sigf(v);
        v *= al;
        if (res) v += res[(size_t)(row0 + r) * ldc + col];
        v4[r] = v;
      }
      if (vtc) {
        const int cm = col - vt0;
        const int hh = cm >> 6, dd = cm & 63;
        const int bb = row0 >> 10, nl = row0 & 1023;
        ushort4 o4 = {f2bfn(v4[0]), f2bfn(v4[1]), f2bfn(v4[2]), f2bfn(v4[3])};
        *(ushort4*)&VTout[((size_t)((bb * 8 + hh) * 64 + dd)) * 1024 + nl] = o4;
      } else {
#pragma unroll
        for (int r = 0; r < 4; ++r) {
          const size_t off = (size_t)(row0 + r) * ldc + col;
          if (Cf) Cf[off] = v4[r];
          else Cb[off] = f2bfn(v4[r]);
        }
      }
    }
  }
}

// ---------------------------------------------------------------- flash attention (MFMA)
// q64 tile, 4 waves; merged in-place SP buffer; Q pre-scaled by 0.125*log2e;
// streaming softmax (bounded scores), deferred denominator reduce.
// K/V staged with global_load_lds into stride-64 double buffers with a
// 16B-block XOR source-side swizzle; one barrier per tile (prefetch spans the
// compute phase). SP is wave-local (no barriers). Native bf16 casts.
// XCD swizzle: all 16 q-tiles of one (b,h) on one XCD (lin&127 = hb).
__global__ __launch_bounds__(256) void attn_mfma(const u16* __restrict__ QKV,
    const u16* __restrict__ Vt, const u16* __restrict__ Rb, u16* __restrict__ O) {
  const int lin = blockIdx.x;
  const int hb = lin & 127;            // (b,h) group
  const int n0 = (lin >> 7) * 64;      // q-tile
  const int h = hb & 7, b = hb >> 3;
  const int t = threadIdx.x;
  const int w = t >> 6;
  const int lc = t & 15, lq = (t >> 4) & 3;

  __shared__ __align__(16) u16 Ks[2][64 * 64];
  __shared__ __align__(16) u16 Vs[2][64 * 64];
  __shared__ __align__(16) u16 SP[64 * 72];   // pos scatter, then exp(S) in place

  bf16x8 qf[2];
  {
    const size_t qrow = (size_t)(b * 1024 + n0 + w * 16 + lc) * 1536 + h * 64;
    qf[0] = *(const bf16x8*)&QKV[qrow + lq * 8];
    qf[1] = *(const bf16x8*)&QKV[qrow + 32 + lq * 8];
  }

  const u16* Kg = QKV + (size_t)b * 1024 * 1536 + 512 + h * 64;  // + j*1536 + c
  const u16* Vg = Vt + (size_t)(b * 8 + h) * 64 * 1024;          // + d*1024 + j

  const int srow = t >> 3;
  const int scb0 = ((t & 7) ^ (srow & 7)) * 8;
  const int srow1 = (t + 256) >> 3;
  const int scb1 = (((t + 256) & 7) ^ (srow1 & 7)) * 8;

  gl_lds16(&Kg[(size_t)srow * 1536 + scb0], &Ks[0][t * 8]);
  gl_lds16(&Vg[(size_t)srow * 1024 + scb0], &Vs[0][t * 8]);
  gl_lds16(&Kg[(size_t)srow1 * 1536 + scb1], &Ks[0][(t + 256) * 8]);
  gl_lds16(&Vg[(size_t)srow1 * 1024 + scb1], &Vs[0][(t + 256) * 8]);

  float l_r[4] = {0.f, 0.f, 0.f, 0.f};
  f32x4 o[4];
#pragma unroll
  for (int dt = 0; dt < 4; ++dt)
#pragma unroll
    for (int r = 0; r < 4; ++r) o[dt][r] = 0.f;

  const int swz0 = (lq ^ (lc & 7)) * 8;        // ks=0 fragment offset
  const int swz1 = ((4 + lq) ^ (lc & 7)) * 8;  // ks=1 fragment offset

  int buf = 0;
  for (int jt = 0; jt < 16; ++jt) {
    const int j0 = jt * 64;
    __syncthreads();   // waits vmcnt(0): prefetched tile complete; buf^1 free

    if (jt < 15) {
      const int j1 = j0 + 64;
      gl_lds16(&Kg[(size_t)(j1 + srow) * 1536 + scb0], &Ks[buf ^ 1][t * 8]);
      gl_lds16(&Vg[(size_t)srow * 1024 + j1 + scb0], &Vs[buf ^ 1][t * 8]);
      gl_lds16(&Kg[(size_t)(j1 + srow1) * 1536 + scb1], &Ks[buf ^ 1][(t + 256) * 8]);
      gl_lds16(&Vg[(size_t)srow1 * 1024 + j1 + scb1], &Vs[buf ^ 1][(t + 256) * 8]);
    }

    f32x4 qk[4], pa[5];
#pragma unroll
    for (int j = 0; j < 4; ++j)
#pragma unroll
      for (int r = 0; r < 4; ++r) qk[j][r] = 0.f;
#pragma unroll
    for (int rtl = 0; rtl < 5; ++rtl)
#pragma unroll
      for (int r = 0; r < 4; ++r) pa[rtl][r] = 0.f;

    const int base = n0 - j0 - 63;
    const u16* rp[5];
#pragma unroll
    for (int rtl = 0; rtl < 5; ++rtl) {
      int p = base + (w + rtl) * 16 + lc;
      p = (p < -512 ? -512 : (p > 512 ? 512 : p)) + 512;
      rp[rtl] = Rb + (size_t)p * 64 + lq * 8;
    }

#pragma unroll
    for (int ks = 0; ks < 2; ++ks) {
      const int koff = ks ? swz1 : swz0;
      bf16x8 rfr[5];
#pragma unroll
      for (int rtl = 0; rtl < 5; ++rtl)
        rfr[rtl] = *(const bf16x8*)&rp[rtl][ks * 32];
#pragma unroll
      for (int j = 0; j < 4; ++j) {
        const bf16x8 bf = *(const bf16x8*)&Ks[buf][(j * 16 + lc) * 64 + koff];
        qk[j] = __builtin_amdgcn_mfma_f32_16x16x32_bf16(qf[ks], bf, qk[j], 0, 0, 0);
      }
#pragma unroll
      for (int rtl = 0; rtl < 5; ++rtl)
        pa[rtl] = __builtin_amdgcn_mfma_f32_16x16x32_bf16(qf[ks], rfr[rtl], pa[rtl], 0, 0, 0);
    }

#pragma unroll
    for (int rtl = 0; rtl < 5; ++rtl) {
      const int didx = (w + rtl) * 16 + lc;
#pragma unroll
      for (int r = 0; r < 4; ++r) {
        const int qr = w * 16 + lq * 4 + r;
        const int jc = qr - didx + 63;
        if ((unsigned)jc < 64u) SP[qr * 72 + jc] = f2bfn(pa[rtl][r]);
      }
    }

#pragma unroll
    for (int r = 0; r < 4; ++r) {
      const int qr = w * 16 + lq * 4 + r;
#pragma unroll
      for (int ti = 0; ti < 4; ++ti) {
        const int a = qr * 72 + ti * 16 + lc;
        const float e = exp2f(qk[ti][r] + bf2f(SP[a]));
        SP[a] = f2bfn(e);
        l_r[r] += e;
      }
    }

#pragma unroll
    for (int ks = 0; ks < 2; ++ks) {
      const bf16x8 af = *(const bf16x8*)&SP[(w * 16 + lc) * 72 + ks * 32 + lq * 8];
      const int koff = ks ? swz1 : swz0;
#pragma unroll
      for (int dt = 0; dt < 4; ++dt) {
        const bf16x8 bf = *(const bf16x8*)&Vs[buf][(dt * 16 + lc) * 64 + koff];
        o[dt] = __builtin_amdgcn_mfma_f32_16x16x32_bf16(af, bf, o[dt], 0, 0, 0);
      }
    }
    buf ^= 1;
  }

#pragma unroll
  for (int r = 0; r < 4; ++r) {
#pragma unroll
    for (int msk = 1; msk < 16; msk <<= 1) l_r[r] += __shfl_xor(l_r[r], msk);
  }

#pragma unroll
  for (int r = 0; r < 4; ++r) {
    const float inv = 1.f / l_r[r];
    const size_t row = (size_t)(b * 1024 + n0 + w * 16 + lq * 4 + r);
#pragma unroll
    for (int dt = 0; dt < 4; ++dt)
      O[row * 512 + h * 64 + dt * 16 + lc] = f2bfn(o[dt][r] * inv);
  }
}

// ---------------------------------------------------------------- depthwise conv (GLU fused)
__global__ __launch_bounds__(256) void dwconv_kernel(const u16* __restrict__ in,
    const float* __restrict__ w, const float* __restrict__ bias,
    u16* __restrict__ out) {
  const int n0 = blockIdx.x * 64;
  const int c0 = blockIdx.y * 64;
  const int b = blockIdx.z;
  const int t = threadIdx.x;
  __shared__ float hs[94][64];
  __shared__ float wsh[31][64];
  const int c = t & 63;
  const int g = t >> 6;
  for (int r = g; r < 94; r += 4) {
    const int n = n0 - 30 + r;
    float v = 0.f;
    if (n >= 0) {
      const size_t rowb = (size_t)(b * 1024 + n) * 2048;
      const float a = bf2f(in[rowb + c0 + c]);
      const float gg = bf2f(in[rowb + 1024 + c0 + c]);
      v = a * sigf(gg);
    }
    hs[r][c] = v;
  }
  for (int idx = t; idx < 31 * 64; idx += 256) {
    const int tap = idx >> 6, cc = idx & 63;
    wsh[tap][cc] = w[(size_t)(c0 + cc) * 31 + tap];
  }
  __syncthreads();
  float wr[31];
#pragma unroll
  for (int k = 0; k < 31; ++k) wr[k] = wsh[k][c];
  const float bsv = bias[c0 + c];
  float win[46];
  const int rbase = g * 16;
#pragma unroll
  for (int k = 0; k < 46; ++k) win[k] = hs[rbase + k][c];
#pragma unroll
  for (int i = 0; i < 16; ++i) {
    float acc = bsv;
#pragma unroll
    for (int k = 0; k < 31; ++k) acc += wr[k] * win[i + k];
    acc = acc * sigf(acc);
    out[(size_t)(b * 1024 + n0 + rbase + i) * 1024 + c0 + c] = f2bfn(acc);
  }
}

// ---------------------------------------------------------------- launch
extern "C" void kernel_launch(void* const* d_in, const int* in_sizes, int n_in,
                              void* d_out, int out_size, void* d_ws, size_t ws_size,
                              hipStream_t stream) {
  const float* x        = (const float*)d_in[0];
  const float* ff1_ln_g = (const float*)d_in[1];
  const float* ff1_ln_b = (const float*)d_in[2];
  const float* ff1_w1   = (const float*)d_in[3];
  const float* ff1_b1   = (const float*)d_in[4];
  const float* ff1_w2   = (const float*)d_in[5];
  const float* ff1_b2   = (const float*)d_in[6];
  const float* attn_ln_g= (const float*)d_in[7];
  const float* attn_ln_b= (const float*)d_in[8];
  const float* wq       = (const float*)d_in[9];
  const float* wkv      = (const float*)d_in[10];
  const float* wo       = (const float*)d_in[11];
  const float* bo       = (const float*)d_in[12];
  const float* rel_emb  = (const float*)d_in[13];
  const float* conv_ln_g= (const float*)d_in[14];
  const float* conv_ln_b= (const float*)d_in[15];
  const float* conv1_w  = (const float*)d_in[16];
  const float* conv1_b  = (const float*)d_in[17];
  const float* dw_w     = (const float*)d_in[18];
  const float* dw_b     = (const float*)d_in[19];
  const float* conv2_w  = (const float*)d_in[20];
  const float* conv2_b  = (const float*)d_in[21];
  const float* ff2_ln_g = (const float*)d_in[22];
  const float* ff2_ln_b = (const float*)d_in[23];
  const float* ff2_w1   = (const float*)d_in[24];
  const float* ff2_b1   = (const float*)d_in[25];
  const float* ff2_w2   = (const float*)d_in[26];
  const float* ff2_b2   = (const float*)d_in[27];
  const float* post_ln_g= (const float*)d_in[28];
  const float* post_ln_b= (const float*)d_in[29];

  float* XRES = (float*)d_out;
  u16* ws = (u16*)d_ws;
  u16* LNB  = ws;                                // BN*512
  u16* HID  = LNB + (size_t)BN * 512;            // BN*2048
  u16* QKVB = HID + (size_t)BN * 2048;           // BN*1536
  u16* VT   = QKVB + (size_t)BN * 1536;          // 8192*1024
  u16* DWB  = QKVB;                              // alias (QKV dead after attn)
  u16* WTp = VT + (size_t)8192 * 1024;
  u16* wt_ff1w1 = WTp;                 WTp += (size_t)2048 * 512;
  u16* wt_ff1w2 = WTp;                 WTp += (size_t)512 * 2048;
  u16* wt_qkv   = WTp;                 WTp += (size_t)1536 * 512;
  u16* wt_wo    = WTp;                 WTp += (size_t)512 * 512;
  u16* wt_conv1 = WTp;                 WTp += (size_t)2048 * 512;
  u16* wt_conv2 = WTp;                 WTp += (size_t)512 * 1024;
  u16* wt_ff2w1 = WTp;                 WTp += (size_t)2048 * 512;
  u16* wt_ff2w2 = WTp;                 WTp += (size_t)512 * 2048;
  u16* RELB     = WTp;

  const dim3 blk(256);
  const float SC = 0.125f * 1.44269504f;  // folded into Q projection

  // weight prep
  wtrans<<<dim3(64, 16), blk, 0, stream>>>(ff1_w1, wt_ff1w1, 512, 2048);
  wtrans<<<dim3(16, 64), blk, 0, stream>>>(ff1_w2, wt_ff1w2, 2048, 512);
  wtrans<<<dim3(16, 16), blk, 0, stream>>>(wq, wt_qkv, 512, 512);
  wtrans<<<dim3(32, 16), blk, 0, stream>>>(wkv, wt_qkv + (size_t)512 * 512, 512, 1024);
  wtrans<<<dim3(16, 16), blk, 0, stream>>>(wo, wt_wo, 512, 512);
  wtrans<<<dim3(64, 16), blk, 0, stream>>>(conv1_w, wt_conv1, 512, 2048);
  wtrans<<<dim3(16, 32), blk, 0, stream>>>(conv2_w, wt_conv2, 1024, 512);
  wtrans<<<dim3(64, 16), blk, 0, stream>>>(ff2_w1, wt_ff2w1, 512, 2048);
  wtrans<<<dim3(16, 64), blk, 0, stream>>>(ff2_w2, wt_ff2w2, 2048, 512);
  cvt_bf16<<<257, blk, 0, stream>>>(rel_emb, RELB, 1025 * 64);

  // --- FF1 (half-step)
  ln_kernel<<<BN / 2, blk, 0, stream>>>(x, ff1_ln_g, ff1_ln_b, LNB, nullptr);
  gemm256<<<dim3(8, 64), dim3(512), 0, stream>>>(LNB, wt_ff1w1, ff1_b1, HID, 512, 2048, 1);
  gemm_bf16<<<dim3(4, 128), blk, 0, stream>>>(HID, wt_ff1w2, ff1_b2, x,
                                              XRES, nullptr, nullptr, 2048, 512, 512, 0.5f, 0, 512, 0);

  // --- attention (merged QKV projection: Q cols scaled by SC, V cols >=1024
  //     written transposed into VT; K row-major)
  ln_kernel<<<BN / 2, blk, 0, stream>>>(XRES, attn_ln_g, attn_ln_b, LNB, nullptr);
  gemm_bf16<<<dim3(12, 128), blk, 0, stream>>>(LNB, wt_qkv, nullptr, nullptr,
                                               nullptr, QKVB, VT, 512, 1536, 1536, SC, 0, 512, 1024);
  attn_mfma<<<dim3(2048), blk, 0, stream>>>(QKVB, VT, RELB, LNB);
  gemm_bf16<<<dim3(4, 128), blk, 0, stream>>>(LNB, wt_wo, bo, XRES,
                                              XRES, nullptr, nullptr, 512, 512, 512, 1.f, 0, 512, 0);

  // --- conv module (GLU fused into dwconv; HID -> DWB directly)
  ln_kernel<<<BN / 2, blk, 0, stream>>>(XRES, conv_ln_g, conv_ln_b, LNB, nullptr);
  gemm256<<<dim3(8, 64), dim3(512), 0, stream>>>(LNB, wt_conv1, conv1_b, HID, 512, 2048, 0);
  dwconv_kernel<<<dim3(16, 16, 16), blk, 0, stream>>>(HID, dw_w, dw_b, DWB);
  gemm_bf16<<<dim3(4, 128), blk, 0, stream>>>(DWB, wt_conv2, conv2_b, XRES,
                                              XRES, nullptr, nullptr, 1024, 512, 512, 1.f, 0, 512, 0);

  // --- FF2 (half-step)
  ln_kernel<<<BN / 2, blk, 0, stream>>>(XRES, ff2_ln_g, ff2_ln_b, LNB, nullptr);
  gemm256<<<dim3(8, 64), dim3(512), 0, stream>>>(LNB, wt_ff2w1, ff2_b1, HID, 512, 2048, 1);
  gemm_bf16<<<dim3(4, 128), blk, 0, stream>>>(HID, wt_ff2w2, ff2_b2, XRES,
                                              XRES, nullptr, nullptr, 2048, 512, 512, 0.5f, 0, 512, 0);

  // --- final layernorm
  ln_kernel<<<BN / 2, blk, 0, stream>>>(XRES, post_ln_g, post_ln_b, nullptr, XRES);
}

// Round 11
// 829.502 us; speedup vs baseline: 1.2430x; 1.0400x over previous
//
#include <hip/hip_runtime.h>

// Conformer block — bf16 MFMA everywhere; round 17 (base = r16, 862us):
// * attn: (1) s_setprio(1) around the QK+rel and PV MFMA clusters (T5);
//   (2) sliding rel window — tile jt+1's rfr[4] == tile jt's rfr[0]
//   (clamp commutes with the -64 shift), carried in registers: 8 instead of
//   10 scattered rel gathers per tile.
// * dwconv: GLU hs-fill vectorized (ushort4 loads, float4 LDS stores).
// * everything else identical to r16 (gemm256 2-phase for wide GEMMs,
//   128^2 gemm elsewhere, fused GLU, 2-row LN).
// B=16 N=1024 DIM=512 H=8 DH=64 FF=2048 CIN=1024 K=31 MAXPOS=512. BN=16384.

#define BN 16384

typedef unsigned short u16;
typedef __attribute__((ext_vector_type(8))) __bf16 bf16x8;
typedef __attribute__((ext_vector_type(4))) float f32x4;
typedef __attribute__((ext_vector_type(8))) unsigned short u16x8;

__device__ __forceinline__ float sigf(float x) { return 1.f / (1.f + __expf(-x)); }
__device__ __forceinline__ u16 f2bf(float f) {
  unsigned int u = __float_as_uint(f);
  u += 0x7FFF + ((u >> 16) & 1);
  return (u16)(u >> 16);
}
__device__ __forceinline__ u16 f2bfn(float f) {
  const __bf16 h = (__bf16)f;
  return __builtin_bit_cast(u16, h);
}
__device__ __forceinline__ float bf2f(u16 u) {
  return __uint_as_float(((unsigned int)u) << 16);
}
__device__ __forceinline__ void gl_lds16(const void* g, void* lds) {
  __builtin_amdgcn_global_load_lds(
      (const __attribute__((address_space(1))) unsigned int*)g,
      (__attribute__((address_space(3))) unsigned int*)lds, 16, 0, 0);
}

// ---------------------------------------------------------------- layernorm
// 2 rows per block; 128 threads/row, float4 (16B) loads.
__global__ __launch_bounds__(256) void ln_kernel(const float* __restrict__ in,
    const float* __restrict__ g, const float* __restrict__ b,
    u16* outb, float* outf) {
  const int t = threadIdx.x;
  const int row = blockIdx.x * 2 + (t >> 7);
  const int tl = t & 127;
  const float4 v = ((const float4*)(in + (size_t)row * 512))[tl];
  float s = v.x + v.y + v.z + v.w;
  float sq = v.x * v.x + v.y * v.y + v.z * v.z + v.w * v.w;
#pragma unroll
  for (int o = 32; o > 0; o >>= 1) {
    s += __shfl_down(s, o);
    sq += __shfl_down(sq, o);
  }
  __shared__ float ss[4], ssq[4];
  if ((t & 63) == 0) { ss[t >> 6] = s; ssq[t >> 6] = sq; }
  __syncthreads();
  const int base = (t >> 7) * 2;
  s = ss[base] + ss[base + 1];
  sq = ssq[base] + ssq[base + 1];
  const float mu = s * (1.f / 512.f);
  const float var = fmaxf(sq * (1.f / 512.f) - mu * mu, 0.f);
  const float rstd = rsqrtf(var + 1e-5f);
  const float4 gg = ((const float4*)g)[tl];
  const float4 bb = ((const float4*)b)[tl];
  float o0 = (v.x - mu) * rstd * gg.x + bb.x;
  float o1 = (v.y - mu) * rstd * gg.y + bb.y;
  float o2 = (v.z - mu) * rstd * gg.z + bb.z;
  float o3 = (v.w - mu) * rstd * gg.w + bb.w;
  if (outf) {
    float4 o4 = {o0, o1, o2, o3};
    ((float4*)(outf + (size_t)row * 512))[tl] = o4;
  } else {
    ushort4 u4 = {f2bf(o0), f2bf(o1), f2bf(o2), f2bf(o3)};
    ((ushort4*)(outb + (size_t)row * 512))[tl] = u4;
  }
}

// ---------------------------------------------------------------- weight prep
__global__ __launch_bounds__(256) void wtrans(const float* __restrict__ W,
                                              u16* __restrict__ WT, int K, int N) {
  const int n0 = blockIdx.x * 32, k0 = blockIdx.y * 32;
  const int t = threadIdx.x;
  const int tx = t & 31, ty = t >> 5;
  __shared__ float T[32][33];
#pragma unroll
  for (int i = 0; i < 4; ++i)
    T[tx][ty + 8 * i] = W[(size_t)(k0 + ty + 8 * i) * N + n0 + tx];
  __syncthreads();
#pragma unroll
  for (int i = 0; i < 4; ++i)
    WT[(size_t)(n0 + ty + 8 * i) * K + k0 + tx] = f2bf(T[ty + 8 * i][tx]);
}

__global__ __launch_bounds__(256) void cvt_bf16(const float* __restrict__ in,
                                                u16* __restrict__ out, int n) {
  const int i = blockIdx.x * 256 + threadIdx.x;
  if (i < n) out[i] = f2bf(in[i]);
}

// ---------------------------------------------------------------- 256^2 2-phase GEMM
// 256x256 tile, 8 waves (2M x 4N), BK=64, double-buffered 128KB LDS,
// one __syncthreads per K-step (stage next BEFORE compute). 16B-chunk XOR
// swizzle. Epilogue bounces C through the freed LDS, stores u16x8.
// Requires: M%256==0, N%256==0, K%128==0. XCD swizzle: m-band per XCD.
__global__ __launch_bounds__(512) void gemm256(const u16* __restrict__ A,
    const u16* __restrict__ WT, const float* __restrict__ bias,
    u16* __restrict__ Cb, int K, int ldc, int act) {
  __shared__ __align__(16) u16 LDSB[65536];   // 128 KB
  u16* const As0 = LDSB;                      // 256x64
  u16* const As1 = LDSB + 16384;
  u16* const Bs0 = LDSB + 32768;
  u16* const Bs1 = LDSB + 49152;
  const int t = threadIdx.x;
  int bx = blockIdx.x, by = blockIdx.y;
  {
    const int nx = gridDim.x;
    const int lin = bx + nx * by;
    const int xcd = lin & 7;
    const int s = lin >> 3;
    const int ny8 = gridDim.y >> 3;
    const int sy = s / nx;
    by = xcd * ny8 + sy;
    bx = s - sy * nx;
  }
  const int n0 = bx * 256;
  const int m0 = by * 256;
  const int w = t >> 6;
  const int wr = w >> 2, wc = w & 3;          // 2M x 4N wave grid
  const int lc = t & 15, lq = (t >> 4) & 3;

  f32x4 acc[8][4];
#pragma unroll
  for (int i = 0; i < 8; ++i)
#pragma unroll
    for (int j = 0; j < 4; ++j)
#pragma unroll
      for (int r = 0; r < 4; ++r) acc[i][j][r] = 0.f;

  int sfr[4], sfc[4];
#pragma unroll
  for (int s = 0; s < 4; ++s) {
    const int f = t + 512 * s;
    sfr[s] = f >> 3;
    sfc[s] = ((f & 7) ^ (sfr[s] & 7)) * 8;
  }

  auto STAGE = [&](u16* Ad, u16* Bd, int kt) {
#pragma unroll
    for (int s = 0; s < 4; ++s) {
      gl_lds16(&A[(size_t)(m0 + sfr[s]) * K + kt + sfc[s]], &Ad[(t + 512 * s) * 8]);
      gl_lds16(&WT[(size_t)(n0 + sfr[s]) * K + kt + sfc[s]], &Bd[(t + 512 * s) * 8]);
    }
  };

  auto COMPUTE = [&](const u16* Asrc, const u16* Bsrc) {
#pragma unroll
    for (int kk = 0; kk < 2; ++kk) {
      const int koff = ((kk * 4 + lq) ^ (lc & 7)) * 8;
      bf16x8 bfr[4];
#pragma unroll
      for (int j = 0; j < 4; ++j)
        bfr[j] = *(const bf16x8*)&Bsrc[(wc * 64 + j * 16 + lc) * 64 + koff];
#pragma unroll
      for (int i = 0; i < 8; ++i) {
        const bf16x8 af = *(const bf16x8*)&Asrc[(wr * 128 + i * 16 + lc) * 64 + koff];
#pragma unroll
        for (int j = 0; j < 4; ++j)
          acc[i][j] = __builtin_amdgcn_mfma_f32_16x16x32_bf16(af, bfr[j], acc[i][j], 0, 0, 0);
      }
    }
  };

  STAGE(As0, Bs0, 0);
  __syncthreads();

  for (int kt2 = 0; kt2 < K; kt2 += 128) {
    STAGE(As1, Bs1, kt2 + 64);
    COMPUTE(As0, Bs0);
    __syncthreads();
    if (kt2 + 128 < K) STAGE(As0, Bs0, kt2 + 128);
    COMPUTE(As1, Bs1);
    __syncthreads();
  }

#pragma unroll
  for (int j = 0; j < 4; ++j) {
    const int coll = wc * 64 + j * 16 + lc;
    const float bj = bias[n0 + coll];
#pragma unroll
    for (int i = 0; i < 8; ++i) {
      const int rowl0 = wr * 128 + i * 16 + lq * 4;
#pragma unroll
      for (int r = 0; r < 4; ++r) {
        float v = acc[i][j][r] + bj;
        if (act) v = v * sigf(v);
        LDSB[(rowl0 + r) * 256 + coll] = f2bfn(v);
      }
    }
  }
  __syncthreads();
#pragma unroll
  for (int vv = 0; vv < 16; ++vv) {
    const int e = t + 512 * vv;
    *(u16x8*)&Cb[(size_t)(m0 + (e >> 5)) * ldc + n0 + (e & 31) * 8] =
        *(const u16x8*)&LDSB[e * 8];
  }
}

// ---------------------------------------------------------------- bf16 MFMA gemm (128^2)
__global__ __launch_bounds__(256) void gemm_bf16(const u16* __restrict__ A,
    const u16* __restrict__ WT, const float* __restrict__ bias,
    const float* res, float* Cf, u16* Cb, u16* VTout, int K, int N, int ldc,
    float alpha, int act, int qn, int vt0) {
  __shared__ __align__(16) u16 Ast[128 * 64];
  __shared__ __align__(16) u16 Bst[128 * 64];
  const int t = threadIdx.x;
  int bx = blockIdx.x, by = blockIdx.y;
  {
    const int nx = gridDim.x;
    const int lin = bx + nx * by;
    const int xcd = lin & 7;
    const int s = lin >> 3;
    const int ny8 = gridDim.y >> 3;
    const int sy = s / nx;
    by = xcd * ny8 + sy;
    bx = s - sy * nx;
  }
  const int n0 = bx * 128;
  const int m0 = by * 128;
  const int w = t >> 6;
  const int lc = t & 15, lq = (t >> 4) & 3;
  const int wy = w >> 1, wx = w & 1;
  f32x4 acc[4][4];
#pragma unroll
  for (int i = 0; i < 4; ++i)
#pragma unroll
    for (int j = 0; j < 4; ++j)
#pragma unroll
      for (int r = 0; r < 4; ++r) acc[i][j][r] = 0.f;

  const int koff0 = (lq ^ (lc & 7)) * 8;
  const int koff1 = ((4 + lq) ^ (lc & 7)) * 8;

  for (int kt = 0; kt < K; kt += 64) {
#pragma unroll
    for (int s = 0; s < 4; ++s) {
      const int f = t + 256 * s;
      const int fr = f >> 3;
      const int fc = (f & 7) ^ (fr & 7);
      gl_lds16(&A[(size_t)(m0 + fr) * K + kt + fc * 8], &Ast[f * 8]);
      gl_lds16(&WT[(size_t)(n0 + fr) * K + kt + fc * 8], &Bst[f * 8]);
    }
    __syncthreads();
#pragma unroll
    for (int kk = 0; kk < 2; ++kk) {
      const int koff = kk ? koff1 : koff0;
      bf16x8 bfr[4];
#pragma unroll
      for (int j = 0; j < 4; ++j)
        bfr[j] = *(const bf16x8*)&Bst[(wx * 64 + j * 16 + lc) * 64 + koff];
#pragma unroll
      for (int i = 0; i < 4; ++i) {
        const bf16x8 af = *(const bf16x8*)&Ast[(wy * 64 + i * 16 + lc) * 64 + koff];
#pragma unroll
        for (int j = 0; j < 4; ++j)
          acc[i][j] = __builtin_amdgcn_mfma_f32_16x16x32_bf16(af, bfr[j], acc[i][j], 0, 0, 0);
      }
    }
    __syncthreads();
  }

  const bool vtblk = (VTout != nullptr) && (n0 >= vt0);
  if (Cb && !vtblk) {
#pragma unroll
    for (int j = 0; j < 4; ++j) {
      const int coll = wx * 64 + j * 16 + lc;
      const float bj = bias ? bias[n0 + coll] : 0.f;
      const float al = ((n0 + coll) < qn) ? alpha : 1.f;
#pragma unroll
      for (int i = 0; i < 4; ++i) {
        const int rowl0 = wy * 64 + i * 16 + lq * 4;
#pragma unroll
        for (int r = 0; r < 4; ++r) {
          float v = acc[i][j][r] + bj;
          if (act) v = v * sigf(v);
          v *= al;
          const int rowl = rowl0 + r;
          u16* cl = (rowl < 64) ? &Ast[rowl * 128] : &Bst[(rowl - 64) * 128];
          cl[coll] = f2bfn(v);
        }
      }
    }
    __syncthreads();
#pragma unroll
    for (int vv = 0; vv < 8; ++vv) {
      const int e = t + 256 * vv;
      const int rowl = e >> 4;
      const int col = (e & 15) * 8;
      const u16* cl = (rowl < 64) ? &Ast[rowl * 128] : &Bst[(rowl - 64) * 128];
      const u16x8 val = *(const u16x8*)&cl[col];
      *(u16x8*)&Cb[(size_t)(m0 + rowl) * ldc + n0 + col] = val;
    }
    return;
  }

#pragma unroll
  for (int j = 0; j < 4; ++j) {
    const int col = n0 + wx * 64 + j * 16 + lc;
    const float bj = bias ? bias[col] : 0.f;
    const float al = (col < qn) ? alpha : 1.f;
    const bool vtc = vtblk && (col >= vt0);
#pragma unroll
    for (int i = 0; i < 4; ++i) {
      const int row0 = m0 + wy * 64 + i * 16 + lq * 4;
      float v4[4];
#pragma unroll
      for (int r = 0; r < 4; ++r) {
        float v = acc[i][j][r] + bj;
        if (act) v = v * sigf(v);
        v *= al;
        if (res) v += res[(size_t)(row0 + r) * ldc + col];
        v4[r] = v;
      }
      if (vtc) {
        const int cm = col - vt0;
        const int hh = cm >> 6, dd = cm & 63;
        const int bb = row0 >> 10, nl = row0 & 1023;
        ushort4 o4 = {f2bfn(v4[0]), f2bfn(v4[1]), f2bfn(v4[2]), f2bfn(v4[3])};
        *(ushort4*)&VTout[((size_t)((bb * 8 + hh) * 64 + dd)) * 1024 + nl] = o4;
      } else {
#pragma unroll
        for (int r = 0; r < 4; ++r) {
          const size_t off = (size_t)(row0 + r) * ldc + col;
          if (Cf) Cf[off] = v4[r];
          else Cb[off] = f2bfn(v4[r]);
        }
      }
    }
  }
}

// ---------------------------------------------------------------- flash attention (MFMA)
// q64 tile, 4 waves; merged in-place SP buffer; Q pre-scaled by 0.125*log2e;
// streaming softmax (bounded scores), deferred denominator reduce.
// K/V staged with global_load_lds into stride-64 double buffers with a
// 16B-block XOR source-side swizzle; one barrier per tile. SP is wave-local.
// r17: setprio(1) around MFMA clusters; sliding rel window (tile jt+1's
// rfr[4] == tile jt's rfr[0]; clamp commutes with the -64 shift) -> 8
// instead of 10 scattered rel gathers per tile.
// XCD swizzle: all 16 q-tiles of one (b,h) on one XCD (lin&127 = hb).
__global__ __launch_bounds__(256) void attn_mfma(const u16* __restrict__ QKV,
    const u16* __restrict__ Vt, const u16* __restrict__ Rb, u16* __restrict__ O) {
  const int lin = blockIdx.x;
  const int hb = lin & 127;            // (b,h) group
  const int n0 = (lin >> 7) * 64;      // q-tile
  const int h = hb & 7, b = hb >> 3;
  const int t = threadIdx.x;
  const int w = t >> 6;
  const int lc = t & 15, lq = (t >> 4) & 3;

  __shared__ __align__(16) u16 Ks[2][64 * 64];
  __shared__ __align__(16) u16 Vs[2][64 * 64];
  __shared__ __align__(16) u16 SP[64 * 72];   // pos scatter, then exp(S) in place

  bf16x8 qf[2];
  {
    const size_t qrow = (size_t)(b * 1024 + n0 + w * 16 + lc) * 1536 + h * 64;
    qf[0] = *(const bf16x8*)&QKV[qrow + lq * 8];
    qf[1] = *(const bf16x8*)&QKV[qrow + 32 + lq * 8];
  }

  const u16* Kg = QKV + (size_t)b * 1024 * 1536 + 512 + h * 64;  // + j*1536 + c
  const u16* Vg = Vt + (size_t)(b * 8 + h) * 64 * 1024;          // + d*1024 + j

  const int srow = t >> 3;
  const int scb0 = ((t & 7) ^ (srow & 7)) * 8;
  const int srow1 = (t + 256) >> 3;
  const int scb1 = (((t + 256) & 7) ^ (srow1 & 7)) * 8;

  gl_lds16(&Kg[(size_t)srow * 1536 + scb0], &Ks[0][t * 8]);
  gl_lds16(&Vg[(size_t)srow * 1024 + scb0], &Vs[0][t * 8]);
  gl_lds16(&Kg[(size_t)srow1 * 1536 + scb1], &Ks[0][(t + 256) * 8]);
  gl_lds16(&Vg[(size_t)srow1 * 1024 + scb1], &Vs[0][(t + 256) * 8]);

  float l_r[4] = {0.f, 0.f, 0.f, 0.f};
  f32x4 o[4];
#pragma unroll
  for (int dt = 0; dt < 4; ++dt)
#pragma unroll
    for (int r = 0; r < 4; ++r) o[dt][r] = 0.f;

  const int swz0 = (lq ^ (lc & 7)) * 8;        // ks=0 fragment offset
  const int swz1 = ((4 + lq) ^ (lc & 7)) * 8;  // ks=1 fragment offset

  bf16x8 rsave[2];                             // rfr[0] of previous tile

  int buf = 0;
  for (int jt = 0; jt < 16; ++jt) {
    const int j0 = jt * 64;
    __syncthreads();   // waits vmcnt(0): prefetched tile complete; buf^1 free

    if (jt < 15) {
      const int j1 = j0 + 64;
      gl_lds16(&Kg[(size_t)(j1 + srow) * 1536 + scb0], &Ks[buf ^ 1][t * 8]);
      gl_lds16(&Vg[(size_t)srow * 1024 + j1 + scb0], &Vs[buf ^ 1][t * 8]);
      gl_lds16(&Kg[(size_t)(j1 + srow1) * 1536 + scb1], &Ks[buf ^ 1][(t + 256) * 8]);
      gl_lds16(&Vg[(size_t)srow1 * 1024 + j1 + scb1], &Vs[buf ^ 1][(t + 256) * 8]);
    }

    f32x4 qk[4], pa[5];
#pragma unroll
    for (int j = 0; j < 4; ++j)
#pragma unroll
      for (int r = 0; r < 4; ++r) qk[j][r] = 0.f;
#pragma unroll
    for (int rtl = 0; rtl < 5; ++rtl)
#pragma unroll
      for (int r = 0; r < 4; ++r) pa[rtl][r] = 0.f;

    // rel row pointers rtl 0..3; rtl=4 slides from last tile's rfr[0]
    // (pointer still computed for jt==0's initial load)
    const int base = n0 - j0 - 63;
    const u16* rp[4];
#pragma unroll
    for (int rtl = 0; rtl < 4; ++rtl) {
      int p = base + (w + rtl) * 16 + lc;
      p = (p < -512 ? -512 : (p > 512 ? 512 : p)) + 512;
      rp[rtl] = Rb + (size_t)p * 64 + lq * 8;
    }
    const u16* rp4;
    {
      int p = base + (w + 4) * 16 + lc;
      p = (p < -512 ? -512 : (p > 512 ? 512 : p)) + 512;
      rp4 = Rb + (size_t)p * 64 + lq * 8;
    }

    __builtin_amdgcn_s_setprio(1);
#pragma unroll
    for (int ks = 0; ks < 2; ++ks) {
      const int koff = ks ? swz1 : swz0;
      bf16x8 rfr[4];
#pragma unroll
      for (int rtl = 0; rtl < 4; ++rtl)
        rfr[rtl] = *(const bf16x8*)&rp[rtl][ks * 32];
      const bf16x8 rfr4 = (jt == 0) ? *(const bf16x8*)&rp4[ks * 32] : rsave[ks];
#pragma unroll
      for (int j = 0; j < 4; ++j) {
        const bf16x8 bf = *(const bf16x8*)&Ks[buf][(j * 16 + lc) * 64 + koff];
        qk[j] = __builtin_amdgcn_mfma_f32_16x16x32_bf16(qf[ks], bf, qk[j], 0, 0, 0);
      }
#pragma unroll
      for (int rtl = 0; rtl < 4; ++rtl)
        pa[rtl] = __builtin_amdgcn_mfma_f32_16x16x32_bf16(qf[ks], rfr[rtl], pa[rtl], 0, 0, 0);
      pa[4] = __builtin_amdgcn_mfma_f32_16x16x32_bf16(qf[ks], rfr4, pa[4], 0, 0, 0);
      rsave[ks] = rfr[0];
    }
    __builtin_amdgcn_s_setprio(0);

    // skewed scatter: P[qr][didx] -> SP[qr][jc], jc = qr - didx + 63 (wave-local)
#pragma unroll
    for (int rtl = 0; rtl < 5; ++rtl) {
      const int didx = (w + rtl) * 16 + lc;
#pragma unroll
      for (int r = 0; r < 4; ++r) {
        const int qr = w * 16 + lq * 4 + r;
        const int jc = qr - didx + 63;
        if ((unsigned)jc < 64u) SP[qr * 72 + jc] = f2bfn(pa[rtl][r]);
      }
    }

    // streaming softmax in place
#pragma unroll
    for (int r = 0; r < 4; ++r) {
      const int qr = w * 16 + lq * 4 + r;
#pragma unroll
      for (int ti = 0; ti < 4; ++ti) {
        const int a = qr * 72 + ti * 16 + lc;
        const float e = exp2f(qk[ti][r] + bf2f(SP[a]));
        SP[a] = f2bfn(e);
        l_r[r] += e;
      }
    }

    // PV
    __builtin_amdgcn_s_setprio(1);
#pragma unroll
    for (int ks = 0; ks < 2; ++ks) {
      const bf16x8 af = *(const bf16x8*)&SP[(w * 16 + lc) * 72 + ks * 32 + lq * 8];
      const int koff = ks ? swz1 : swz0;
#pragma unroll
      for (int dt = 0; dt < 4; ++dt) {
        const bf16x8 bf = *(const bf16x8*)&Vs[buf][(dt * 16 + lc) * 64 + koff];
        o[dt] = __builtin_amdgcn_mfma_f32_16x16x32_bf16(af, bf, o[dt], 0, 0, 0);
      }
    }
    __builtin_amdgcn_s_setprio(0);
    buf ^= 1;
  }

#pragma unroll
  for (int r = 0; r < 4; ++r) {
#pragma unroll
    for (int msk = 1; msk < 16; msk <<= 1) l_r[r] += __shfl_xor(l_r[r], msk);
  }

#pragma unroll
  for (int r = 0; r < 4; ++r) {
    const float inv = 1.f / l_r[r];
    const size_t row = (size_t)(b * 1024 + n0 + w * 16 + lq * 4 + r);
#pragma unroll
    for (int dt = 0; dt < 4; ++dt)
      O[row * 512 + h * 64 + dt * 16 + lc] = f2bfn(o[dt][r] * inv);
  }
}

// ---------------------------------------------------------------- depthwise conv (GLU fused)
// in = HID (2048 cols): h = a*sig(g) computed in the hs-fill loop.
// r17: fill vectorized — ushort4 loads (8B), float4 LDS stores.
__global__ __launch_bounds__(256) void dwconv_kernel(const u16* __restrict__ in,
    const float* __restrict__ w, const float* __restrict__ bias,
    u16* __restrict__ out) {
  const int n0 = blockIdx.x * 64;
  const int c0 = blockIdx.y * 64;
  const int b = blockIdx.z;
  const int t = threadIdx.x;
  __shared__ float hs[94][64];
  __shared__ float wsh[31][64];
  const int c = t & 63;
  const int g = t >> 6;
  {
    const int cg = (t & 15) * 4;   // 4 consecutive cols
    const int rg = t >> 4;         // 16 row groups
    for (int r = rg; r < 94; r += 16) {
      const int n = n0 - 30 + r;
      float4 v4 = {0.f, 0.f, 0.f, 0.f};
      if (n >= 0) {
        const size_t rowb = (size_t)(b * 1024 + n) * 2048;
        const ushort4 a4 = *(const ushort4*)&in[rowb + c0 + cg];
        const ushort4 g4 = *(const ushort4*)&in[rowb + 1024 + c0 + cg];
        v4.x = bf2f(a4.x) * sigf(bf2f(g4.x));
        v4.y = bf2f(a4.y) * sigf(bf2f(g4.y));
        v4.z = bf2f(a4.z) * sigf(bf2f(g4.z));
        v4.w = bf2f(a4.w) * sigf(bf2f(g4.w));
      }
      *(float4*)&hs[r][cg] = v4;
    }
  }
  for (int idx = t; idx < 31 * 64; idx += 256) {
    const int tap = idx >> 6, cc = idx & 63;
    wsh[tap][cc] = w[(size_t)(c0 + cc) * 31 + tap];
  }
  __syncthreads();
  float wr[31];
#pragma unroll
  for (int k = 0; k < 31; ++k) wr[k] = wsh[k][c];
  const float bsv = bias[c0 + c];
  float win[46];
  const int rbase = g * 16;
#pragma unroll
  for (int k = 0; k < 46; ++k) win[k] = hs[rbase + k][c];
#pragma unroll
  for (int i = 0; i < 16; ++i) {
    float acc = bsv;
#pragma unroll
    for (int k = 0; k < 31; ++k) acc += wr[k] * win[i + k];
    acc = acc * sigf(acc);
    out[(size_t)(b * 1024 + n0 + rbase + i) * 1024 + c0 + c] = f2bfn(acc);
  }
}

// ---------------------------------------------------------------- launch
extern "C" void kernel_launch(void* const* d_in, const int* in_sizes, int n_in,
                              void* d_out, int out_size, void* d_ws, size_t ws_size,
                              hipStream_t stream) {
  const float* x        = (const float*)d_in[0];
  const float* ff1_ln_g = (const float*)d_in[1];
  const float* ff1_ln_b = (const float*)d_in[2];
  const float* ff1_w1   = (const float*)d_in[3];
  const float* ff1_b1   = (const float*)d_in[4];
  const float* ff1_w2   = (const float*)d_in[5];
  const float* ff1_b2   = (const float*)d_in[6];
  const float* attn_ln_g= (const float*)d_in[7];
  const float* attn_ln_b= (const float*)d_in[8];
  const float* wq       = (const float*)d_in[9];
  const float* wkv      = (const float*)d_in[10];
  const float* wo       = (const float*)d_in[11];
  const float* bo       = (const float*)d_in[12];
  const float* rel_emb  = (const float*)d_in[13];
  const float* conv_ln_g= (const float*)d_in[14];
  const float* conv_ln_b= (const float*)d_in[15];
  const float* conv1_w  = (const float*)d_in[16];
  const float* conv1_b  = (const float*)d_in[17];
  const float* dw_w     = (const float*)d_in[18];
  const float* dw_b     = (const float*)d_in[19];
  const float* conv2_w  = (const float*)d_in[20];
  const float* conv2_b  = (const float*)d_in[21];
  const float* ff2_ln_g = (const float*)d_in[22];
  const float* ff2_ln_b = (const float*)d_in[23];
  const float* ff2_w1   = (const float*)d_in[24];
  const float* ff2_b1   = (const float*)d_in[25];
  const float* ff2_w2   = (const float*)d_in[26];
  const float* ff2_b2   = (const float*)d_in[27];
  const float* post_ln_g= (const float*)d_in[28];
  const float* post_ln_b= (const float*)d_in[29];

  float* XRES = (float*)d_out;
  u16* ws = (u16*)d_ws;
  u16* LNB  = ws;                                // BN*512
  u16* HID  = LNB + (size_t)BN * 512;            // BN*2048
  u16* QKVB = HID + (size_t)BN * 2048;           // BN*1536
  u16* VT   = QKVB + (size_t)BN * 1536;          // 8192*1024
  u16* DWB  = QKVB;                              // alias (QKV dead after attn)
  u16* WTp = VT + (size_t)8192 * 1024;
  u16* wt_ff1w1 = WTp;                 WTp += (size_t)2048 * 512;
  u16* wt_ff1w2 = WTp;                 WTp += (size_t)512 * 2048;
  u16* wt_qkv   = WTp;                 WTp += (size_t)1536 * 512;
  u16* wt_wo    = WTp;                 WTp += (size_t)512 * 512;
  u16* wt_conv1 = WTp;                 WTp += (size_t)2048 * 512;
  u16* wt_conv2 = WTp;                 WTp += (size_t)512 * 1024;
  u16* wt_ff2w1 = WTp;                 WTp += (size_t)2048 * 512;
  u16* wt_ff2w2 = WTp;                 WTp += (size_t)512 * 2048;
  u16* RELB     = WTp;

  const dim3 blk(256);
  const float SC = 0.125f * 1.44269504f;  // folded into Q projection

  // weight prep
  wtrans<<<dim3(64, 16), blk, 0, stream>>>(ff1_w1, wt_ff1w1, 512, 2048);
  wtrans<<<dim3(16, 64), blk, 0, stream>>>(ff1_w2, wt_ff1w2, 2048, 512);
  wtrans<<<dim3(16, 16), blk, 0, stream>>>(wq, wt_qkv, 512, 512);
  wtrans<<<dim3(32, 16), blk, 0, stream>>>(wkv, wt_qkv + (size_t)512 * 512, 512, 1024);
  wtrans<<<dim3(16, 16), blk, 0, stream>>>(wo, wt_wo, 512, 512);
  wtrans<<<dim3(64, 16), blk, 0, stream>>>(conv1_w, wt_conv1, 512, 2048);
  wtrans<<<dim3(16, 32), blk, 0, stream>>>(conv2_w, wt_conv2, 1024, 512);
  wtrans<<<dim3(64, 16), blk, 0, stream>>>(ff2_w1, wt_ff2w1, 512, 2048);
  wtrans<<<dim3(16, 64), blk, 0, stream>>>(ff2_w2, wt_ff2w2, 2048, 512);
  cvt_bf16<<<257, blk, 0, stream>>>(rel_emb, RELB, 1025 * 64);

  // --- FF1 (half-step)
  ln_kernel<<<BN / 2, blk, 0, stream>>>(x, ff1_ln_g, ff1_ln_b, LNB, nullptr);
  gemm256<<<dim3(8, 64), dim3(512), 0, stream>>>(LNB, wt_ff1w1, ff1_b1, HID, 512, 2048, 1);
  gemm_bf16<<<dim3(4, 128), blk, 0, stream>>>(HID, wt_ff1w2, ff1_b2, x,
                                              XRES, nullptr, nullptr, 2048, 512, 512, 0.5f, 0, 512, 0);

  // --- attention (merged QKV projection: Q cols scaled by SC, V cols >=1024
  //     written transposed into VT; K row-major)
  ln_kernel<<<BN / 2, blk, 0, stream>>>(XRES, attn_ln_g, attn_ln_b, LNB, nullptr);
  gemm_bf16<<<dim3(12, 128), blk, 0, stream>>>(LNB, wt_qkv, nullptr, nullptr,
                                               nullptr, QKVB, VT, 512, 1536, 1536, SC, 0, 512, 1024);
  attn_mfma<<<dim3(2048), blk, 0, stream>>>(QKVB, VT, RELB, LNB);
  gemm_bf16<<<dim3(4, 128), blk, 0, stream>>>(LNB, wt_wo, bo, XRES,
                                              XRES, nullptr, nullptr, 512, 512, 512, 1.f, 0, 512, 0);

  // --- conv module (GLU fused into dwconv; HID -> DWB directly)
  ln_kernel<<<BN / 2, blk, 0, stream>>>(XRES, conv_ln_g, conv_ln_b, LNB, nullptr);
  gemm256<<<dim3(8, 64), dim3(512), 0, stream>>>(LNB, wt_conv1, conv1_b, HID, 512, 2048, 0);
  dwconv_kernel<<<dim3(16, 16, 16), blk, 0, stream>>>(HID, dw_w, dw_b, DWB);
  gemm_bf16<<<dim3(4, 128), blk, 0, stream>>>(DWB, wt_conv2, conv2_b, XRES,
                                              XRES, nullptr, nullptr, 1024, 512, 512, 1.f, 0, 512, 0);

  // --- FF2 (half-step)
  ln_kernel<<<BN / 2, blk, 0, stream>>>(XRES, ff2_ln_g, ff2_ln_b, LNB, nullptr);
  gemm256<<<dim3(8, 64), dim3(512), 0, stream>>>(LNB, wt_ff2w1, ff2_b1, HID, 512, 2048, 1);
  gemm_bf16<<<dim3(4, 128), blk, 0, stream>>>(HID, wt_ff2w2, ff2_b2, XRES,
                                              XRES, nullptr, nullptr, 2048, 512, 512, 0.5f, 0, 512, 0);

  // --- final layernorm
  ln_kernel<<<BN / 2, blk, 0, stream>>>(XRES, post_ln_g, post_ln_b, nullptr, XRES);
}

// Round 12
// 803.118 us; speedup vs baseline: 1.2838x; 1.0329x over previous
//
#include <hip/hip_runtime.h>

// Conformer block — bf16 MFMA everywhere; round 18 (base = r17, 829.5us):
// * gemm_bf16: f32-C + residual epilogue now bounces the C-tile through LDS
//   in two 64-row halves (Ast/Bst merged into one 32KB buffer => contiguous
//   64x128 f32 view). Wave writes acc -> barrier -> 256 threads stream 8x
//   float4 {LDS read, coalesced res load, add, coalesced store}. Replaces
//   64 scalar res loads + 64 scalar stores per thread (4x 64B segments per
//   wave instr) with 32 fully-coalesced vector ops. Applies to ff1w2, wo,
//   conv2, ff2w2.
// * everything else identical to r17 (attn setprio+sliding-rel at 174us,
//   gemm256 2-phase wide GEMMs, fused GLU+dwconv vectorized, 2-row LN).
// B=16 N=1024 DIM=512 H=8 DH=64 FF=2048 CIN=1024 K=31 MAXPOS=512. BN=16384.

#define BN 16384

typedef unsigned short u16;
typedef __attribute__((ext_vector_type(8))) __bf16 bf16x8;
typedef __attribute__((ext_vector_type(4))) float f32x4;
typedef __attribute__((ext_vector_type(8))) unsigned short u16x8;

__device__ __forceinline__ float sigf(float x) { return 1.f / (1.f + __expf(-x)); }
__device__ __forceinline__ u16 f2bf(float f) {
  unsigned int u = __float_as_uint(f);
  u += 0x7FFF + ((u >> 16) & 1);
  return (u16)(u >> 16);
}
__device__ __forceinline__ u16 f2bfn(float f) {
  const __bf16 h = (__bf16)f;
  return __builtin_bit_cast(u16, h);
}
__device__ __forceinline__ float bf2f(u16 u) {
  return __uint_as_float(((unsigned int)u) << 16);
}
__device__ __forceinline__ void gl_lds16(const void* g, void* lds) {
  __builtin_amdgcn_global_load_lds(
      (const __attribute__((address_space(1))) unsigned int*)g,
      (__attribute__((address_space(3))) unsigned int*)lds, 16, 0, 0);
}

// ---------------------------------------------------------------- layernorm
// 2 rows per block; 128 threads/row, float4 (16B) loads.
__global__ __launch_bounds__(256) void ln_kernel(const float* __restrict__ in,
    const float* __restrict__ g, const float* __restrict__ b,
    u16* outb, float* outf) {
  const int t = threadIdx.x;
  const int row = blockIdx.x * 2 + (t >> 7);
  const int tl = t & 127;
  const float4 v = ((const float4*)(in + (size_t)row * 512))[tl];
  float s = v.x + v.y + v.z + v.w;
  float sq = v.x * v.x + v.y * v.y + v.z * v.z + v.w * v.w;
#pragma unroll
  for (int o = 32; o > 0; o >>= 1) {
    s += __shfl_down(s, o);
    sq += __shfl_down(sq, o);
  }
  __shared__ float ss[4], ssq[4];
  if ((t & 63) == 0) { ss[t >> 6] = s; ssq[t >> 6] = sq; }
  __syncthreads();
  const int base = (t >> 7) * 2;
  s = ss[base] + ss[base + 1];
  sq = ssq[base] + ssq[base + 1];
  const float mu = s * (1.f / 512.f);
  const float var = fmaxf(sq * (1.f / 512.f) - mu * mu, 0.f);
  const float rstd = rsqrtf(var + 1e-5f);
  const float4 gg = ((const float4*)g)[tl];
  const float4 bb = ((const float4*)b)[tl];
  float o0 = (v.x - mu) * rstd * gg.x + bb.x;
  float o1 = (v.y - mu) * rstd * gg.y + bb.y;
  float o2 = (v.z - mu) * rstd * gg.z + bb.z;
  float o3 = (v.w - mu) * rstd * gg.w + bb.w;
  if (outf) {
    float4 o4 = {o0, o1, o2, o3};
    ((float4*)(outf + (size_t)row * 512))[tl] = o4;
  } else {
    ushort4 u4 = {f2bf(o0), f2bf(o1), f2bf(o2), f2bf(o3)};
    ((ushort4*)(outb + (size_t)row * 512))[tl] = u4;
  }
}

// ---------------------------------------------------------------- weight prep
__global__ __launch_bounds__(256) void wtrans(const float* __restrict__ W,
                                              u16* __restrict__ WT, int K, int N) {
  const int n0 = blockIdx.x * 32, k0 = blockIdx.y * 32;
  const int t = threadIdx.x;
  const int tx = t & 31, ty = t >> 5;
  __shared__ float T[32][33];
#pragma unroll
  for (int i = 0; i < 4; ++i)
    T[tx][ty + 8 * i] = W[(size_t)(k0 + ty + 8 * i) * N + n0 + tx];
  __syncthreads();
#pragma unroll
  for (int i = 0; i < 4; ++i)
    WT[(size_t)(n0 + ty + 8 * i) * K + k0 + tx] = f2bf(T[ty + 8 * i][tx]);
}

__global__ __launch_bounds__(256) void cvt_bf16(const float* __restrict__ in,
                                                u16* __restrict__ out, int n) {
  const int i = blockIdx.x * 256 + threadIdx.x;
  if (i < n) out[i] = f2bf(in[i]);
}

// ---------------------------------------------------------------- 256^2 2-phase GEMM
// 256x256 tile, 8 waves (2M x 4N), BK=64, double-buffered 128KB LDS,
// one __syncthreads per K-step (stage next BEFORE compute). 16B-chunk XOR
// swizzle. Epilogue bounces C through the freed LDS, stores u16x8.
// Requires: M%256==0, N%256==0, K%128==0. XCD swizzle: m-band per XCD.
__global__ __launch_bounds__(512) void gemm256(const u16* __restrict__ A,
    const u16* __restrict__ WT, const float* __restrict__ bias,
    u16* __restrict__ Cb, int K, int ldc, int act) {
  __shared__ __align__(16) u16 LDSB[65536];   // 128 KB
  u16* const As0 = LDSB;                      // 256x64
  u16* const As1 = LDSB + 16384;
  u16* const Bs0 = LDSB + 32768;
  u16* const Bs1 = LDSB + 49152;
  const int t = threadIdx.x;
  int bx = blockIdx.x, by = blockIdx.y;
  {
    const int nx = gridDim.x;
    const int lin = bx + nx * by;
    const int xcd = lin & 7;
    const int s = lin >> 3;
    const int ny8 = gridDim.y >> 3;
    const int sy = s / nx;
    by = xcd * ny8 + sy;
    bx = s - sy * nx;
  }
  const int n0 = bx * 256;
  const int m0 = by * 256;
  const int w = t >> 6;
  const int wr = w >> 2, wc = w & 3;          // 2M x 4N wave grid
  const int lc = t & 15, lq = (t >> 4) & 3;

  f32x4 acc[8][4];
#pragma unroll
  for (int i = 0; i < 8; ++i)
#pragma unroll
    for (int j = 0; j < 4; ++j)
#pragma unroll
      for (int r = 0; r < 4; ++r) acc[i][j][r] = 0.f;

  int sfr[4], sfc[4];
#pragma unroll
  for (int s = 0; s < 4; ++s) {
    const int f = t + 512 * s;
    sfr[s] = f >> 3;
    sfc[s] = ((f & 7) ^ (sfr[s] & 7)) * 8;
  }

  auto STAGE = [&](u16* Ad, u16* Bd, int kt) {
#pragma unroll
    for (int s = 0; s < 4; ++s) {
      gl_lds16(&A[(size_t)(m0 + sfr[s]) * K + kt + sfc[s]], &Ad[(t + 512 * s) * 8]);
      gl_lds16(&WT[(size_t)(n0 + sfr[s]) * K + kt + sfc[s]], &Bd[(t + 512 * s) * 8]);
    }
  };

  auto COMPUTE = [&](const u16* Asrc, const u16* Bsrc) {
#pragma unroll
    for (int kk = 0; kk < 2; ++kk) {
      const int koff = ((kk * 4 + lq) ^ (lc & 7)) * 8;
      bf16x8 bfr[4];
#pragma unroll
      for (int j = 0; j < 4; ++j)
        bfr[j] = *(const bf16x8*)&Bsrc[(wc * 64 + j * 16 + lc) * 64 + koff];
#pragma unroll
      for (int i = 0; i < 8; ++i) {
        const bf16x8 af = *(const bf16x8*)&Asrc[(wr * 128 + i * 16 + lc) * 64 + koff];
#pragma unroll
        for (int j = 0; j < 4; ++j)
          acc[i][j] = __builtin_amdgcn_mfma_f32_16x16x32_bf16(af, bfr[j], acc[i][j], 0, 0, 0);
      }
    }
  };

  STAGE(As0, Bs0, 0);
  __syncthreads();

  for (int kt2 = 0; kt2 < K; kt2 += 128) {
    STAGE(As1, Bs1, kt2 + 64);
    COMPUTE(As0, Bs0);
    __syncthreads();
    if (kt2 + 128 < K) STAGE(As0, Bs0, kt2 + 128);
    COMPUTE(As1, Bs1);
    __syncthreads();
  }

#pragma unroll
  for (int j = 0; j < 4; ++j) {
    const int coll = wc * 64 + j * 16 + lc;
    const float bj = bias[n0 + coll];
#pragma unroll
    for (int i = 0; i < 8; ++i) {
      const int rowl0 = wr * 128 + i * 16 + lq * 4;
#pragma unroll
      for (int r = 0; r < 4; ++r) {
        float v = acc[i][j][r] + bj;
        if (act) v = v * sigf(v);
        LDSB[(rowl0 + r) * 256 + coll] = f2bfn(v);
      }
    }
  }
  __syncthreads();
#pragma unroll
  for (int vv = 0; vv < 16; ++vv) {
    const int e = t + 512 * vv;
    *(u16x8*)&Cb[(size_t)(m0 + (e >> 5)) * ldc + n0 + (e & 31) * 8] =
        *(const u16x8*)&LDSB[e * 8];
  }
}

// ---------------------------------------------------------------- bf16 MFMA gemm (128^2)
// BK=64, 16B-chunk XOR swizzle, 2 barriers/K-step. Epilogues:
//  * bf16-C: bounce through SH, u16x8 stores (r13).
//  * f32-C + res (r18): bounce in two 64-row halves through SH as f32
//    (64x128x4B = 32KB), then stream float4 {LDS read, res load, add, store}
//    — fully coalesced res reads and C writes.
//  * VT blocks: transposed ushort4 path.
__global__ __launch_bounds__(256) void gemm_bf16(const u16* __restrict__ A,
    const u16* __restrict__ WT, const float* __restrict__ bias,
    const float* res, float* Cf, u16* Cb, u16* VTout, int K, int N, int ldc,
    float alpha, int act, int qn, int vt0) {
  __shared__ __align__(16) u16 SH[16384];     // 32 KB: Ast | Bst
  u16* const Ast = SH;                        // 128x64
  u16* const Bst = SH + 8192;                 // 128x64
  const int t = threadIdx.x;
  int bx = blockIdx.x, by = blockIdx.y;
  {
    const int nx = gridDim.x;
    const int lin = bx + nx * by;
    const int xcd = lin & 7;
    const int s = lin >> 3;
    const int ny8 = gridDim.y >> 3;
    const int sy = s / nx;
    by = xcd * ny8 + sy;
    bx = s - sy * nx;
  }
  const int n0 = bx * 128;
  const int m0 = by * 128;
  const int w = t >> 6;
  const int lc = t & 15, lq = (t >> 4) & 3;
  const int wy = w >> 1, wx = w & 1;
  f32x4 acc[4][4];
#pragma unroll
  for (int i = 0; i < 4; ++i)
#pragma unroll
    for (int j = 0; j < 4; ++j)
#pragma unroll
      for (int r = 0; r < 4; ++r) acc[i][j][r] = 0.f;

  const int koff0 = (lq ^ (lc & 7)) * 8;
  const int koff1 = ((4 + lq) ^ (lc & 7)) * 8;

  for (int kt = 0; kt < K; kt += 64) {
#pragma unroll
    for (int s = 0; s < 4; ++s) {
      const int f = t + 256 * s;
      const int fr = f >> 3;
      const int fc = (f & 7) ^ (fr & 7);
      gl_lds16(&A[(size_t)(m0 + fr) * K + kt + fc * 8], &Ast[f * 8]);
      gl_lds16(&WT[(size_t)(n0 + fr) * K + kt + fc * 8], &Bst[f * 8]);
    }
    __syncthreads();
#pragma unroll
    for (int kk = 0; kk < 2; ++kk) {
      const int koff = kk ? koff1 : koff0;
      bf16x8 bfr[4];
#pragma unroll
      for (int j = 0; j < 4; ++j)
        bfr[j] = *(const bf16x8*)&Bst[(wx * 64 + j * 16 + lc) * 64 + koff];
#pragma unroll
      for (int i = 0; i < 4; ++i) {
        const bf16x8 af = *(const bf16x8*)&Ast[(wy * 64 + i * 16 + lc) * 64 + koff];
#pragma unroll
        for (int j = 0; j < 4; ++j)
          acc[i][j] = __builtin_amdgcn_mfma_f32_16x16x32_bf16(af, bfr[j], acc[i][j], 0, 0, 0);
      }
    }
    __syncthreads();
  }

  const bool vtblk = (VTout != nullptr) && (n0 >= vt0);

  if (Cf && res) {
    // ---- f32 C + residual via two-half LDS bounce (r18) ----
    float* const CL = (float*)SH;             // 64 x 128 f32 view
#pragma unroll
    for (int half = 0; half < 2; ++half) {
      if (half) __syncthreads();              // half-0 reads done before overwrite
      if (wy == half) {
#pragma unroll
        for (int j = 0; j < 4; ++j) {
          const int coll = wx * 64 + j * 16 + lc;
          const int col = n0 + coll;
          const float bj = bias ? bias[col] : 0.f;
          const float al = (col < qn) ? alpha : 1.f;
#pragma unroll
          for (int i = 0; i < 4; ++i) {
            const int rowl0 = i * 16 + lq * 4;
#pragma unroll
            for (int r = 0; r < 4; ++r) {
              float v = acc[i][j][r] + bj;
              if (act) v = v * sigf(v);
              CL[(rowl0 + r) * 128 + coll] = v * al;
            }
          }
        }
      }
      __syncthreads();
#pragma unroll
      for (int vv = 0; vv < 8; ++vv) {
        const int e = t + 256 * vv;           // 0..2047
        const int rowl = e >> 5;              // 0..63
        const int colf = (e & 31) * 4;        // 0..124
        float4 v4 = *(const float4*)&CL[rowl * 128 + colf];
        const size_t goff = (size_t)(m0 + half * 64 + rowl) * ldc + n0 + colf;
        const float4 r4 = *(const float4*)&res[goff];
        v4.x += r4.x; v4.y += r4.y; v4.z += r4.z; v4.w += r4.w;
        *(float4*)&Cf[goff] = v4;
      }
    }
    return;
  }

  if (Cb && !vtblk) {
    // ---- bf16 C via LDS bounce ----
#pragma unroll
    for (int j = 0; j < 4; ++j) {
      const int coll = wx * 64 + j * 16 + lc;
      const float bj = bias ? bias[n0 + coll] : 0.f;
      const float al = ((n0 + coll) < qn) ? alpha : 1.f;
#pragma unroll
      for (int i = 0; i < 4; ++i) {
        const int rowl0 = wy * 64 + i * 16 + lq * 4;
#pragma unroll
        for (int r = 0; r < 4; ++r) {
          float v = acc[i][j][r] + bj;
          if (act) v = v * sigf(v);
          v *= al;
          const int rowl = rowl0 + r;
          u16* cl = (rowl < 64) ? &Ast[rowl * 128] : &Bst[(rowl - 64) * 128];
          cl[coll] = f2bfn(v);
        }
      }
    }
    __syncthreads();
#pragma unroll
    for (int vv = 0; vv < 8; ++vv) {
      const int e = t + 256 * vv;
      const int rowl = e >> 4;
      const int col = (e & 15) * 8;
      const u16* cl = (rowl < 64) ? &Ast[rowl * 128] : &Bst[(rowl - 64) * 128];
      const u16x8 val = *(const u16x8*)&cl[col];
      *(u16x8*)&Cb[(size_t)(m0 + rowl) * ldc + n0 + col] = val;
    }
    return;
  }

#pragma unroll
  for (int j = 0; j < 4; ++j) {
    const int col = n0 + wx * 64 + j * 16 + lc;
    const float bj = bias ? bias[col] : 0.f;
    const float al = (col < qn) ? alpha : 1.f;
    const bool vtc = vtblk && (col >= vt0);
#pragma unroll
    for (int i = 0; i < 4; ++i) {
      const int row0 = m0 + wy * 64 + i * 16 + lq * 4;
      float v4[4];
#pragma unroll
      for (int r = 0; r < 4; ++r) {
        float v = acc[i][j][r] + bj;
        if (act) v = v * sigf(v);
        v *= al;
        if (res) v += res[(size_t)(row0 + r) * ldc + col];
        v4[r] = v;
      }
      if (vtc) {
        const int cm = col - vt0;
        const int hh = cm >> 6, dd = cm & 63;
        const int bb = row0 >> 10, nl = row0 & 1023;
        ushort4 o4 = {f2bfn(v4[0]), f2bfn(v4[1]), f2bfn(v4[2]), f2bfn(v4[3])};
        *(ushort4*)&VTout[((size_t)((bb * 8 + hh) * 64 + dd)) * 1024 + nl] = o4;
      } else {
#pragma unroll
        for (int r = 0; r < 4; ++r) {
          const size_t off = (size_t)(row0 + r) * ldc + col;
          if (Cf) Cf[off] = v4[r];
          else Cb[off] = f2bfn(v4[r]);
        }
      }
    }
  }
}

// ---------------------------------------------------------------- flash attention (MFMA)
// q64 tile, 4 waves; merged in-place SP buffer; Q pre-scaled by 0.125*log2e;
// streaming softmax (bounded scores), deferred denominator reduce.
// K/V staged with global_load_lds into stride-64 double buffers with a
// 16B-block XOR source-side swizzle; one barrier per tile. SP is wave-local.
// setprio(1) around MFMA clusters; sliding rel window (tile jt+1's rfr[4]
// == tile jt's rfr[0]) -> 8 instead of 10 rel gathers per tile.
// XCD swizzle: all 16 q-tiles of one (b,h) on one XCD (lin&127 = hb).
__global__ __launch_bounds__(256) void attn_mfma(const u16* __restrict__ QKV,
    const u16* __restrict__ Vt, const u16* __restrict__ Rb, u16* __restrict__ O) {
  const int lin = blockIdx.x;
  const int hb = lin & 127;            // (b,h) group
  const int n0 = (lin >> 7) * 64;      // q-tile
  const int h = hb & 7, b = hb >> 3;
  const int t = threadIdx.x;
  const int w = t >> 6;
  const int lc = t & 15, lq = (t >> 4) & 3;

  __shared__ __align__(16) u16 Ks[2][64 * 64];
  __shared__ __align__(16) u16 Vs[2][64 * 64];
  __shared__ __align__(16) u16 SP[64 * 72];   // pos scatter, then exp(S) in place

  bf16x8 qf[2];
  {
    const size_t qrow = (size_t)(b * 1024 + n0 + w * 16 + lc) * 1536 + h * 64;
    qf[0] = *(const bf16x8*)&QKV[qrow + lq * 8];
    qf[1] = *(const bf16x8*)&QKV[qrow + 32 + lq * 8];
  }

  const u16* Kg = QKV + (size_t)b * 1024 * 1536 + 512 + h * 64;  // + j*1536 + c
  const u16* Vg = Vt + (size_t)(b * 8 + h) * 64 * 1024;          // + d*1024 + j

  const int srow = t >> 3;
  const int scb0 = ((t & 7) ^ (srow & 7)) * 8;
  const int srow1 = (t + 256) >> 3;
  const int scb1 = (((t + 256) & 7) ^ (srow1 & 7)) * 8;

  gl_lds16(&Kg[(size_t)srow * 1536 + scb0], &Ks[0][t * 8]);
  gl_lds16(&Vg[(size_t)srow * 1024 + scb0], &Vs[0][t * 8]);
  gl_lds16(&Kg[(size_t)srow1 * 1536 + scb1], &Ks[0][(t + 256) * 8]);
  gl_lds16(&Vg[(size_t)srow1 * 1024 + scb1], &Vs[0][(t + 256) * 8]);

  float l_r[4] = {0.f, 0.f, 0.f, 0.f};
  f32x4 o[4];
#pragma unroll
  for (int dt = 0; dt < 4; ++dt)
#pragma unroll
    for (int r = 0; r < 4; ++r) o[dt][r] = 0.f;

  const int swz0 = (lq ^ (lc & 7)) * 8;        // ks=0 fragment offset
  const int swz1 = ((4 + lq) ^ (lc & 7)) * 8;  // ks=1 fragment offset

  bf16x8 rsave[2];                             // rfr[0] of previous tile

  int buf = 0;
  for (int jt = 0; jt < 16; ++jt) {
    const int j0 = jt * 64;
    __syncthreads();   // waits vmcnt(0): prefetched tile complete; buf^1 free

    if (jt < 15) {
      const int j1 = j0 + 64;
      gl_lds16(&Kg[(size_t)(j1 + srow) * 1536 + scb0], &Ks[buf ^ 1][t * 8]);
      gl_lds16(&Vg[(size_t)srow * 1024 + j1 + scb0], &Vs[buf ^ 1][t * 8]);
      gl_lds16(&Kg[(size_t)(j1 + srow1) * 1536 + scb1], &Ks[buf ^ 1][(t + 256) * 8]);
      gl_lds16(&Vg[(size_t)srow1 * 1024 + j1 + scb1], &Vs[buf ^ 1][(t + 256) * 8]);
    }

    f32x4 qk[4], pa[5];
#pragma unroll
    for (int j = 0; j < 4; ++j)
#pragma unroll
      for (int r = 0; r < 4; ++r) qk[j][r] = 0.f;
#pragma unroll
    for (int rtl = 0; rtl < 5; ++rtl)
#pragma unroll
      for (int r = 0; r < 4; ++r) pa[rtl][r] = 0.f;

    const int base = n0 - j0 - 63;
    const u16* rp[4];
#pragma unroll
    for (int rtl = 0; rtl < 4; ++rtl) {
      int p = base + (w + rtl) * 16 + lc;
      p = (p < -512 ? -512 : (p > 512 ? 512 : p)) + 512;
      rp[rtl] = Rb + (size_t)p * 64 + lq * 8;
    }
    const u16* rp4;
    {
      int p = base + (w + 4) * 16 + lc;
      p = (p < -512 ? -512 : (p > 512 ? 512 : p)) + 512;
      rp4 = Rb + (size_t)p * 64 + lq * 8;
    }

    __builtin_amdgcn_s_setprio(1);
#pragma unroll
    for (int ks = 0; ks < 2; ++ks) {
      const int koff = ks ? swz1 : swz0;
      bf16x8 rfr[4];
#pragma unroll
      for (int rtl = 0; rtl < 4; ++rtl)
        rfr[rtl] = *(const bf16x8*)&rp[rtl][ks * 32];
      const bf16x8 rfr4 = (jt == 0) ? *(const bf16x8*)&rp4[ks * 32] : rsave[ks];
#pragma unroll
      for (int j = 0; j < 4; ++j) {
        const bf16x8 bf = *(const bf16x8*)&Ks[buf][(j * 16 + lc) * 64 + koff];
        qk[j] = __builtin_amdgcn_mfma_f32_16x16x32_bf16(qf[ks], bf, qk[j], 0, 0, 0);
      }
#pragma unroll
      for (int rtl = 0; rtl < 4; ++rtl)
        pa[rtl] = __builtin_amdgcn_mfma_f32_16x16x32_bf16(qf[ks], rfr[rtl], pa[rtl], 0, 0, 0);
      pa[4] = __builtin_amdgcn_mfma_f32_16x16x32_bf16(qf[ks], rfr4, pa[4], 0, 0, 0);
      rsave[ks] = rfr[0];
    }
    __builtin_amdgcn_s_setprio(0);

    // skewed scatter: P[qr][didx] -> SP[qr][jc], jc = qr - didx + 63 (wave-local)
#pragma unroll
    for (int rtl = 0; rtl < 5; ++rtl) {
      const int didx = (w + rtl) * 16 + lc;
#pragma unroll
      for (int r = 0; r < 4; ++r) {
        const int qr = w * 16 + lq * 4 + r;
        const int jc = qr - didx + 63;
        if ((unsigned)jc < 64u) SP[qr * 72 + jc] = f2bfn(pa[rtl][r]);
      }
    }

    // streaming softmax in place
#pragma unroll
    for (int r = 0; r < 4; ++r) {
      const int qr = w * 16 + lq * 4 + r;
#pragma unroll
      for (int ti = 0; ti < 4; ++ti) {
        const int a = qr * 72 + ti * 16 + lc;
        const float e = exp2f(qk[ti][r] + bf2f(SP[a]));
        SP[a] = f2bfn(e);
        l_r[r] += e;
      }
    }

    // PV
    __builtin_amdgcn_s_setprio(1);
#pragma unroll
    for (int ks = 0; ks < 2; ++ks) {
      const bf16x8 af = *(const bf16x8*)&SP[(w * 16 + lc) * 72 + ks * 32 + lq * 8];
      const int koff = ks ? swz1 : swz0;
#pragma unroll
      for (int dt = 0; dt < 4; ++dt) {
        const bf16x8 bf = *(const bf16x8*)&Vs[buf][(dt * 16 + lc) * 64 + koff];
        o[dt] = __builtin_amdgcn_mfma_f32_16x16x32_bf16(af, bf, o[dt], 0, 0, 0);
      }
    }
    __builtin_amdgcn_s_setprio(0);
    buf ^= 1;
  }

#pragma unroll
  for (int r = 0; r < 4; ++r) {
#pragma unroll
    for (int msk = 1; msk < 16; msk <<= 1) l_r[r] += __shfl_xor(l_r[r], msk);
  }

#pragma unroll
  for (int r = 0; r < 4; ++r) {
    const float inv = 1.f / l_r[r];
    const size_t row = (size_t)(b * 1024 + n0 + w * 16 + lq * 4 + r);
#pragma unroll
    for (int dt = 0; dt < 4; ++dt)
      O[row * 512 + h * 64 + dt * 16 + lc] = f2bfn(o[dt][r] * inv);
  }
}

// ---------------------------------------------------------------- depthwise conv (GLU fused)
// in = HID (2048 cols): h = a*sig(g) computed in the hs-fill loop.
// Fill vectorized — ushort4 loads (8B), float4 LDS stores.
__global__ __launch_bounds__(256) void dwconv_kernel(const u16* __restrict__ in,
    const float* __restrict__ w, const float* __restrict__ bias,
    u16* __restrict__ out) {
  const int n0 = blockIdx.x * 64;
  const int c0 = blockIdx.y * 64;
  const int b = blockIdx.z;
  const int t = threadIdx.x;
  __shared__ float hs[94][64];
  __shared__ float wsh[31][64];
  const int c = t & 63;
  const int g = t >> 6;
  {
    const int cg = (t & 15) * 4;   // 4 consecutive cols
    const int rg = t >> 4;         // 16 row groups
    for (int r = rg; r < 94; r += 16) {
      const int n = n0 - 30 + r;
      float4 v4 = {0.f, 0.f, 0.f, 0.f};
      if (n >= 0) {
        const size_t rowb = (size_t)(b * 1024 + n) * 2048;
        const ushort4 a4 = *(const ushort4*)&in[rowb + c0 + cg];
        const ushort4 g4 = *(const ushort4*)&in[rowb + 1024 + c0 + cg];
        v4.x = bf2f(a4.x) * sigf(bf2f(g4.x));
        v4.y = bf2f(a4.y) * sigf(bf2f(g4.y));
        v4.z = bf2f(a4.z) * sigf(bf2f(g4.z));
        v4.w = bf2f(a4.w) * sigf(bf2f(g4.w));
      }
      *(float4*)&hs[r][cg] = v4;
    }
  }
  for (int idx = t; idx < 31 * 64; idx += 256) {
    const int tap = idx >> 6, cc = idx & 63;
    wsh[tap][cc] = w[(size_t)(c0 + cc) * 31 + tap];
  }
  __syncthreads();
  float wr[31];
#pragma unroll
  for (int k = 0; k < 31; ++k) wr[k] = wsh[k][c];
  const float bsv = bias[c0 + c];
  float win[46];
  const int rbase = g * 16;
#pragma unroll
  for (int k = 0; k < 46; ++k) win[k] = hs[rbase + k][c];
#pragma unroll
  for (int i = 0; i < 16; ++i) {
    float acc = bsv;
#pragma unroll
    for (int k = 0; k < 31; ++k) acc += wr[k] * win[i + k];
    acc = acc * sigf(acc);
    out[(size_t)(b * 1024 + n0 + rbase + i) * 1024 + c0 + c] = f2bfn(acc);
  }
}

// ---------------------------------------------------------------- launch
extern "C" void kernel_launch(void* const* d_in, const int* in_sizes, int n_in,
                              void* d_out, int out_size, void* d_ws, size_t ws_size,
                              hipStream_t stream) {
  const float* x        = (const float*)d_in[0];
  const float* ff1_ln_g = (const float*)d_in[1];
  const float* ff1_ln_b = (const float*)d_in[2];
  const float* ff1_w1   = (const float*)d_in[3];
  const float* ff1_b1   = (const float*)d_in[4];
  const float* ff1_w2   = (const float*)d_in[5];
  const float* ff1_b2   = (const float*)d_in[6];
  const float* attn_ln_g= (const float*)d_in[7];
  const float* attn_ln_b= (const float*)d_in[8];
  const float* wq       = (const float*)d_in[9];
  const float* wkv      = (const float*)d_in[10];
  const float* wo       = (const float*)d_in[11];
  const float* bo       = (const float*)d_in[12];
  const float* rel_emb  = (const float*)d_in[13];
  const float* conv_ln_g= (const float*)d_in[14];
  const float* conv_ln_b= (const float*)d_in[15];
  const float* conv1_w  = (const float*)d_in[16];
  const float* conv1_b  = (const float*)d_in[17];
  const float* dw_w     = (const float*)d_in[18];
  const float* dw_b     = (const float*)d_in[19];
  const float* conv2_w  = (const float*)d_in[20];
  const float* conv2_b  = (const float*)d_in[21];
  const float* ff2_ln_g = (const float*)d_in[22];
  const float* ff2_ln_b = (const float*)d_in[23];
  const float* ff2_w1   = (const float*)d_in[24];
  const float* ff2_b1   = (const float*)d_in[25];
  const float* ff2_w2   = (const float*)d_in[26];
  const float* ff2_b2   = (const float*)d_in[27];
  const float* post_ln_g= (const float*)d_in[28];
  const float* post_ln_b= (const float*)d_in[29];

  float* XRES = (float*)d_out;
  u16* ws = (u16*)d_ws;
  u16* LNB  = ws;                                // BN*512
  u16* HID  = LNB + (size_t)BN * 512;            // BN*2048
  u16* QKVB = HID + (size_t)BN * 2048;           // BN*1536
  u16* VT   = QKVB + (size_t)BN * 1536;          // 8192*1024
  u16* DWB  = QKVB;                              // alias (QKV dead after attn)
  u16* WTp = VT + (size_t)8192 * 1024;
  u16* wt_ff1w1 = WTp;                 WTp += (size_t)2048 * 512;
  u16* wt_ff1w2 = WTp;                 WTp += (size_t)512 * 2048;
  u16* wt_qkv   = WTp;                 WTp += (size_t)1536 * 512;
  u16* wt_wo    = WTp;                 WTp += (size_t)512 * 512;
  u16* wt_conv1 = WTp;                 WTp += (size_t)2048 * 512;
  u16* wt_conv2 = WTp;                 WTp += (size_t)512 * 1024;
  u16* wt_ff2w1 = WTp;                 WTp += (size_t)2048 * 512;
  u16* wt_ff2w2 = WTp;                 WTp += (size_t)512 * 2048;
  u16* RELB     = WTp;

  const dim3 blk(256);
  const float SC = 0.125f * 1.44269504f;  // folded into Q projection

  // weight prep
  wtrans<<<dim3(64, 16), blk, 0, stream>>>(ff1_w1, wt_ff1w1, 512, 2048);
  wtrans<<<dim3(16, 64), blk, 0, stream>>>(ff1_w2, wt_ff1w2, 2048, 512);
  wtrans<<<dim3(16, 16), blk, 0, stream>>>(wq, wt_qkv, 512, 512);
  wtrans<<<dim3(32, 16), blk, 0, stream>>>(wkv, wt_qkv + (size_t)512 * 512, 512, 1024);
  wtrans<<<dim3(16, 16), blk, 0, stream>>>(wo, wt_wo, 512, 512);
  wtrans<<<dim3(64, 16), blk, 0, stream>>>(conv1_w, wt_conv1, 512, 2048);
  wtrans<<<dim3(16, 32), blk, 0, stream>>>(conv2_w, wt_conv2, 1024, 512);
  wtrans<<<dim3(64, 16), blk, 0, stream>>>(ff2_w1, wt_ff2w1, 512, 2048);
  wtrans<<<dim3(16, 64), blk, 0, stream>>>(ff2_w2, wt_ff2w2, 2048, 512);
  cvt_bf16<<<257, blk, 0, stream>>>(rel_emb, RELB, 1025 * 64);

  // --- FF1 (half-step)
  ln_kernel<<<BN / 2, blk, 0, stream>>>(x, ff1_ln_g, ff1_ln_b, LNB, nullptr);
  gemm256<<<dim3(8, 64), dim3(512), 0, stream>>>(LNB, wt_ff1w1, ff1_b1, HID, 512, 2048, 1);
  gemm_bf16<<<dim3(4, 128), blk, 0, stream>>>(HID, wt_ff1w2, ff1_b2, x,
                                              XRES, nullptr, nullptr, 2048, 512, 512, 0.5f, 0, 512, 0);

  // --- attention (merged QKV projection: Q cols scaled by SC, V cols >=1024
  //     written transposed into VT; K row-major)
  ln_kernel<<<BN / 2, blk, 0, stream>>>(XRES, attn_ln_g, attn_ln_b, LNB, nullptr);
  gemm_bf16<<<dim3(12, 128), blk, 0, stream>>>(LNB, wt_qkv, nullptr, nullptr,
                                               nullptr, QKVB, VT, 512, 1536, 1536, SC, 0, 512, 1024);
  attn_mfma<<<dim3(2048), blk, 0, stream>>>(QKVB, VT, RELB, LNB);
  gemm_bf16<<<dim3(4, 128), blk, 0, stream>>>(LNB, wt_wo, bo, XRES,
                                              XRES, nullptr, nullptr, 512, 512, 512, 1.f, 0, 512, 0);

  // --- conv module (GLU fused into dwconv; HID -> DWB directly)
  ln_kernel<<<BN / 2, blk, 0, stream>>>(XRES, conv_ln_g, conv_ln_b, LNB, nullptr);
  gemm256<<<dim3(8, 64), dim3(512), 0, stream>>>(LNB, wt_conv1, conv1_b, HID, 512, 2048, 0);
  dwconv_kernel<<<dim3(16, 16, 16), blk, 0, stream>>>(HID, dw_w, dw_b, DWB);
  gemm_bf16<<<dim3(4, 128), blk, 0, stream>>>(DWB, wt_conv2, conv2_b, XRES,
                                              XRES, nullptr, nullptr, 1024, 512, 512, 1.f, 0, 512, 0);

  // --- FF2 (half-step)
  ln_kernel<<<BN / 2, blk, 0, stream>>>(XRES, ff2_ln_g, ff2_ln_b, LNB, nullptr);
  gemm256<<<dim3(8, 64), dim3(512), 0, stream>>>(LNB, wt_ff2w1, ff2_b1, HID, 512, 2048, 1);
  gemm_bf16<<<dim3(4, 128), blk, 0, stream>>>(HID, wt_ff2w2, ff2_b2, XRES,
                                              XRES, nullptr, nullptr, 2048, 512, 512, 0.5f, 0, 512, 0);

  // --- final layernorm
  ln_kernel<<<BN / 2, blk, 0, stream>>>(XRES, post_ln_g, post_ln_b, nullptr, XRES);
}

// Round 13
// 799.378 us; speedup vs baseline: 1.2899x; 1.0047x over previous
//
#include <hip/hip_runtime.h>

// Conformer block — bf16 MFMA everywhere; round 20 (base = r19, 803us):
// * gemm256: counted-vmcnt pipeline (T3+T4+T5). Raw s_barrier + literal
//   s_waitcnt vmcnt(8) (never 0 in the main loop); K=512 -> 8 fully-unrolled
//   K-steps. Per step: {kk0: ds_read frags + 32 MFMA} {kk1: ds_read frags,
//   lgkmcnt(0)+sched_barrier (rule 18), s_barrier [all reads of this buffer
//   done everywhere], STAGE(tile i+2) into it, 32 MFMA under setprio(1),
//   vmcnt(8)+s_barrier [publish tile i+1]}. Prefetched loads stay in flight
//   across barriers with ~600cy of cover — removes the two full vmcnt(0)
//   drains per K-step that __syncthreads imposed (m218: counted-vs-drain0 =
//   +38-73%).
// * everything else identical to r19 (attn setprio+sliding-rel 174us, f32
//   epilogue bounce, fused GLU+dwconv, 2-row LN).
// B=16 N=1024 DIM=512 H=8 DH=64 FF=2048 CIN=1024 K=31 MAXPOS=512. BN=16384.

#define BN 16384

typedef unsigned short u16;
typedef __attribute__((ext_vector_type(8))) __bf16 bf16x8;
typedef __attribute__((ext_vector_type(4))) float f32x4;
typedef __attribute__((ext_vector_type(8))) unsigned short u16x8;

__device__ __forceinline__ float sigf(float x) { return 1.f / (1.f + __expf(-x)); }
__device__ __forceinline__ u16 f2bf(float f) {
  unsigned int u = __float_as_uint(f);
  u += 0x7FFF + ((u >> 16) & 1);
  return (u16)(u >> 16);
}
__device__ __forceinline__ u16 f2bfn(float f) {
  const __bf16 h = (__bf16)f;
  return __builtin_bit_cast(u16, h);
}
__device__ __forceinline__ float bf2f(u16 u) {
  return __uint_as_float(((unsigned int)u) << 16);
}
__device__ __forceinline__ void gl_lds16(const void* g, void* lds) {
  __builtin_amdgcn_global_load_lds(
      (const __attribute__((address_space(1))) unsigned int*)g,
      (__attribute__((address_space(3))) unsigned int*)lds, 16, 0, 0);
}

// ---------------------------------------------------------------- layernorm
// 2 rows per block; 128 threads/row, float4 (16B) loads.
__global__ __launch_bounds__(256) void ln_kernel(const float* __restrict__ in,
    const float* __restrict__ g, const float* __restrict__ b,
    u16* outb, float* outf) {
  const int t = threadIdx.x;
  const int row = blockIdx.x * 2 + (t >> 7);
  const int tl = t & 127;
  const float4 v = ((const float4*)(in + (size_t)row * 512))[tl];
  float s = v.x + v.y + v.z + v.w;
  float sq = v.x * v.x + v.y * v.y + v.z * v.z + v.w * v.w;
#pragma unroll
  for (int o = 32; o > 0; o >>= 1) {
    s += __shfl_down(s, o);
    sq += __shfl_down(sq, o);
  }
  __shared__ float ss[4], ssq[4];
  if ((t & 63) == 0) { ss[t >> 6] = s; ssq[t >> 6] = sq; }
  __syncthreads();
  const int base = (t >> 7) * 2;
  s = ss[base] + ss[base + 1];
  sq = ssq[base] + ssq[base + 1];
  const float mu = s * (1.f / 512.f);
  const float var = fmaxf(sq * (1.f / 512.f) - mu * mu, 0.f);
  const float rstd = rsqrtf(var + 1e-5f);
  const float4 gg = ((const float4*)g)[tl];
  const float4 bb = ((const float4*)b)[tl];
  float o0 = (v.x - mu) * rstd * gg.x + bb.x;
  float o1 = (v.y - mu) * rstd * gg.y + bb.y;
  float o2 = (v.z - mu) * rstd * gg.z + bb.z;
  float o3 = (v.w - mu) * rstd * gg.w + bb.w;
  if (outf) {
    float4 o4 = {o0, o1, o2, o3};
    ((float4*)(outf + (size_t)row * 512))[tl] = o4;
  } else {
    ushort4 u4 = {f2bf(o0), f2bf(o1), f2bf(o2), f2bf(o3)};
    ((ushort4*)(outb + (size_t)row * 512))[tl] = u4;
  }
}

// ---------------------------------------------------------------- weight prep
__global__ __launch_bounds__(256) void wtrans(const float* __restrict__ W,
                                              u16* __restrict__ WT, int K, int N) {
  const int n0 = blockIdx.x * 32, k0 = blockIdx.y * 32;
  const int t = threadIdx.x;
  const int tx = t & 31, ty = t >> 5;
  __shared__ float T[32][33];
#pragma unroll
  for (int i = 0; i < 4; ++i)
    T[tx][ty + 8 * i] = W[(size_t)(k0 + ty + 8 * i) * N + n0 + tx];
  __syncthreads();
#pragma unroll
  for (int i = 0; i < 4; ++i)
    WT[(size_t)(n0 + ty + 8 * i) * K + k0 + tx] = f2bf(T[ty + 8 * i][tx]);
}

__global__ __launch_bounds__(256) void cvt_bf16(const float* __restrict__ in,
                                                u16* __restrict__ out, int n) {
  const int i = blockIdx.x * 256 + threadIdx.x;
  if (i < n) out[i] = f2bf(in[i]);
}

// ---------------------------------------------------------------- 256^2 counted-vmcnt GEMM
// 256x256 tile, 8 waves (2M x 4N), BK=64, double-buffered 128KB LDS.
// K fixed at 512 -> 8 fully-unrolled K-steps, literal vmcnt waits.
// Pipeline (steady state): 2 tiles in flight; the publish wait is vmcnt(8)
// (tile i+1's loads) with the whole previous step as cover — never a full
// drain. Epilogue bounces C through the freed LDS, stores u16x8.
// Requires: M%256==0, N%256==0, K==512. XCD swizzle: m-band per XCD.
__global__ __launch_bounds__(512) void gemm256(const u16* __restrict__ A,
    const u16* __restrict__ WT, const float* __restrict__ bias,
    u16* __restrict__ Cb, int K, int ldc, int act) {
  __shared__ __align__(16) u16 LDSB[65536];   // 128 KB
  u16* const As0 = LDSB;                      // 256x64
  u16* const As1 = LDSB + 16384;
  u16* const Bs0 = LDSB + 32768;
  u16* const Bs1 = LDSB + 49152;
  const int t = threadIdx.x;
  int bx = blockIdx.x, by = blockIdx.y;
  {
    const int nx = gridDim.x;
    const int lin = bx + nx * by;
    const int xcd = lin & 7;
    const int s = lin >> 3;
    const int ny8 = gridDim.y >> 3;
    const int sy = s / nx;
    by = xcd * ny8 + sy;
    bx = s - sy * nx;
  }
  const int n0 = bx * 256;
  const int m0 = by * 256;
  const int w = t >> 6;
  const int wr = w >> 2, wc = w & 3;          // 2M x 4N wave grid
  const int lc = t & 15, lq = (t >> 4) & 3;

  f32x4 acc[8][4];
#pragma unroll
  for (int i = 0; i < 8; ++i)
#pragma unroll
    for (int j = 0; j < 4; ++j)
#pragma unroll
      for (int r = 0; r < 4; ++r) acc[i][j][r] = 0.f;

  int sfr[4], sfc[4];
#pragma unroll
  for (int s = 0; s < 4; ++s) {
    const int f = t + 512 * s;
    sfr[s] = f >> 3;
    sfc[s] = ((f & 7) ^ (sfr[s] & 7)) * 8;
  }

  // 8 vmcnt events per STAGE per wave
  auto STAGE = [&](u16* Ad, u16* Bd, int kt) {
#pragma unroll
    for (int s = 0; s < 4; ++s) {
      gl_lds16(&A[(size_t)(m0 + sfr[s]) * K + kt + sfc[s]], &Ad[(t + 512 * s) * 8]);
      gl_lds16(&WT[(size_t)(n0 + sfr[s]) * K + kt + sfc[s]], &Bd[(t + 512 * s) * 8]);
    }
  };

  const int koff0 = (lq ^ (lc & 7)) * 8;
  const int koff1 = ((4 + lq) ^ (lc & 7)) * 8;

  // prologue: tiles 0,1 in flight; wait only tile 0 (vmcnt(8) = tile 1 pending)
  STAGE(As0, Bs0, 0);
  STAGE(As1, Bs1, 64);
  asm volatile("s_waitcnt vmcnt(8)" ::: "memory");
  __builtin_amdgcn_sched_barrier(0);
  __builtin_amdgcn_s_barrier();               // tile 0 visible to all waves

#pragma unroll
  for (int i = 0; i < 8; ++i) {
    const u16* Asrc = (i & 1) ? As1 : As0;
    const u16* Bsrc = (i & 1) ? Bs1 : Bs0;
    u16* Adst = (i & 1) ? As1 : As0;          // overwritten with tile i+2
    u16* Bdst = (i & 1) ? Bs1 : Bs0;

    // ---- kk=0: frags + MFMA (reads complete via MFMA consumption) ----
    {
      bf16x8 bfr[4], af[8];
#pragma unroll
      for (int j = 0; j < 4; ++j)
        bfr[j] = *(const bf16x8*)&Bsrc[(wc * 64 + j * 16 + lc) * 64 + koff0];
#pragma unroll
      for (int ii = 0; ii < 8; ++ii)
        af[ii] = *(const bf16x8*)&Asrc[(wr * 128 + ii * 16 + lc) * 64 + koff0];
      __builtin_amdgcn_s_setprio(1);
#pragma unroll
      for (int ii = 0; ii < 8; ++ii)
#pragma unroll
        for (int j = 0; j < 4; ++j)
          acc[ii][j] = __builtin_amdgcn_mfma_f32_16x16x32_bf16(af[ii], bfr[j], acc[ii][j], 0, 0, 0);
      __builtin_amdgcn_s_setprio(0);
    }
    // ---- kk=1: frags, complete ALL reads of this buffer, then overwrite ----
    {
      bf16x8 bfr[4], af[8];
#pragma unroll
      for (int j = 0; j < 4; ++j)
        bfr[j] = *(const bf16x8*)&Bsrc[(wc * 64 + j * 16 + lc) * 64 + koff1];
#pragma unroll
      for (int ii = 0; ii < 8; ++ii)
        af[ii] = *(const bf16x8*)&Asrc[(wr * 128 + ii * 16 + lc) * 64 + koff1];
      asm volatile("s_waitcnt lgkmcnt(0)" ::: "memory");
      __builtin_amdgcn_sched_barrier(0);      // rule 18: pin MFMA below the wait
      __builtin_amdgcn_s_barrier();           // all waves done reading this buffer
      if (i + 2 < 8) STAGE(Adst, Bdst, (i + 2) * 64);
      __builtin_amdgcn_s_setprio(1);
#pragma unroll
      for (int ii = 0; ii < 8; ++ii)
#pragma unroll
        for (int j = 0; j < 4; ++j)
          acc[ii][j] = __builtin_amdgcn_mfma_f32_16x16x32_bf16(af[ii], bfr[j], acc[ii][j], 0, 0, 0);
      __builtin_amdgcn_s_setprio(0);
    }
    // ---- publish tile i+1 (counted wait; full drain only at the tail) ----
    if (i < 6) {
      asm volatile("s_waitcnt vmcnt(8)" ::: "memory");
      __builtin_amdgcn_sched_barrier(0);
      __builtin_amdgcn_s_barrier();
    } else if (i == 6) {
      asm volatile("s_waitcnt vmcnt(0)" ::: "memory");
      __builtin_amdgcn_sched_barrier(0);
      __builtin_amdgcn_s_barrier();
    }
    // i == 7: last step; reads already fenced by its kk=1 barrier
  }

  // epilogue: bounce C (256x256 bf16 = 128KB = whole LDS; all reads fenced)
#pragma unroll
  for (int j = 0; j < 4; ++j) {
    const int coll = wc * 64 + j * 16 + lc;
    const float bj = bias[n0 + coll];
#pragma unroll
    for (int i = 0; i < 8; ++i) {
      const int rowl0 = wr * 128 + i * 16 + lq * 4;
#pragma unroll
      for (int r = 0; r < 4; ++r) {
        float v = acc[i][j][r] + bj;
        if (act) v = v * sigf(v);
        LDSB[(rowl0 + r) * 256 + coll] = f2bfn(v);
      }
    }
  }
  __syncthreads();
#pragma unroll
  for (int vv = 0; vv < 16; ++vv) {
    const int e = t + 512 * vv;
    *(u16x8*)&Cb[(size_t)(m0 + (e >> 5)) * ldc + n0 + (e & 31) * 8] =
        *(const u16x8*)&LDSB[e * 8];
  }
}

// ---------------------------------------------------------------- bf16 MFMA gemm (128^2)
// BK=64, 16B-chunk XOR swizzle, 2 barriers/K-step. Epilogues:
//  * bf16-C: bounce through SH, u16x8 stores.
//  * f32-C + res: two-half LDS bounce, float4 streams (r18).
//  * VT blocks: transposed ushort4 path.
__global__ __launch_bounds__(256) void gemm_bf16(const u16* __restrict__ A,
    const u16* __restrict__ WT, const float* __restrict__ bias,
    const float* res, float* Cf, u16* Cb, u16* VTout, int K, int N, int ldc,
    float alpha, int act, int qn, int vt0) {
  __shared__ __align__(16) u16 SH[16384];     // 32 KB: Ast | Bst
  u16* const Ast = SH;                        // 128x64
  u16* const Bst = SH + 8192;                 // 128x64
  const int t = threadIdx.x;
  int bx = blockIdx.x, by = blockIdx.y;
  {
    const int nx = gridDim.x;
    const int lin = bx + nx * by;
    const int xcd = lin & 7;
    const int s = lin >> 3;
    const int ny8 = gridDim.y >> 3;
    const int sy = s / nx;
    by = xcd * ny8 + sy;
    bx = s - sy * nx;
  }
  const int n0 = bx * 128;
  const int m0 = by * 128;
  const int w = t >> 6;
  const int lc = t & 15, lq = (t >> 4) & 3;
  const int wy = w >> 1, wx = w & 1;
  f32x4 acc[4][4];
#pragma unroll
  for (int i = 0; i < 4; ++i)
#pragma unroll
    for (int j = 0; j < 4; ++j)
#pragma unroll
      for (int r = 0; r < 4; ++r) acc[i][j][r] = 0.f;

  const int koff0 = (lq ^ (lc & 7)) * 8;
  const int koff1 = ((4 + lq) ^ (lc & 7)) * 8;

  for (int kt = 0; kt < K; kt += 64) {
#pragma unroll
    for (int s = 0; s < 4; ++s) {
      const int f = t + 256 * s;
      const int fr = f >> 3;
      const int fc = (f & 7) ^ (fr & 7);
      gl_lds16(&A[(size_t)(m0 + fr) * K + kt + fc * 8], &Ast[f * 8]);
      gl_lds16(&WT[(size_t)(n0 + fr) * K + kt + fc * 8], &Bst[f * 8]);
    }
    __syncthreads();
#pragma unroll
    for (int kk = 0; kk < 2; ++kk) {
      const int koff = kk ? koff1 : koff0;
      bf16x8 bfr[4];
#pragma unroll
      for (int j = 0; j < 4; ++j)
        bfr[j] = *(const bf16x8*)&Bst[(wx * 64 + j * 16 + lc) * 64 + koff];
#pragma unroll
      for (int i = 0; i < 4; ++i) {
        const bf16x8 af = *(const bf16x8*)&Ast[(wy * 64 + i * 16 + lc) * 64 + koff];
#pragma unroll
        for (int j = 0; j < 4; ++j)
          acc[i][j] = __builtin_amdgcn_mfma_f32_16x16x32_bf16(af, bfr[j], acc[i][j], 0, 0, 0);
      }
    }
    __syncthreads();
  }

  const bool vtblk = (VTout != nullptr) && (n0 >= vt0);

  if (Cf && res) {
    // ---- f32 C + residual via two-half LDS bounce ----
    float* const CL = (float*)SH;             // 64 x 128 f32 view
#pragma unroll
    for (int half = 0; half < 2; ++half) {
      if (half) __syncthreads();              // half-0 reads done before overwrite
      if (wy == half) {
#pragma unroll
        for (int j = 0; j < 4; ++j) {
          const int coll = wx * 64 + j * 16 + lc;
          const int col = n0 + coll;
          const float bj = bias ? bias[col] : 0.f;
          const float al = (col < qn) ? alpha : 1.f;
#pragma unroll
          for (int i = 0; i < 4; ++i) {
            const int rowl0 = i * 16 + lq * 4;
#pragma unroll
            for (int r = 0; r < 4; ++r) {
              float v = acc[i][j][r] + bj;
              if (act) v = v * sigf(v);
              CL[(rowl0 + r) * 128 + coll] = v * al;
            }
          }
        }
      }
      __syncthreads();
#pragma unroll
      for (int vv = 0; vv < 8; ++vv) {
        const int e = t + 256 * vv;           // 0..2047
        const int rowl = e >> 5;              // 0..63
        const int colf = (e & 31) * 4;        // 0..124
        float4 v4 = *(const float4*)&CL[rowl * 128 + colf];
        const size_t goff = (size_t)(m0 + half * 64 + rowl) * ldc + n0 + colf;
        const float4 r4 = *(const float4*)&res[goff];
        v4.x += r4.x; v4.y += r4.y; v4.z += r4.z; v4.w += r4.w;
        *(float4*)&Cf[goff] = v4;
      }
    }
    return;
  }

  if (Cb && !vtblk) {
    // ---- bf16 C via LDS bounce ----
#pragma unroll
    for (int j = 0; j < 4; ++j) {
      const int coll = wx * 64 + j * 16 + lc;
      const float bj = bias ? bias[n0 + coll] : 0.f;
      const float al = ((n0 + coll) < qn) ? alpha : 1.f;
#pragma unroll
      for (int i = 0; i < 4; ++i) {
        const int rowl0 = wy * 64 + i * 16 + lq * 4;
#pragma unroll
        for (int r = 0; r < 4; ++r) {
          float v = acc[i][j][r] + bj;
          if (act) v = v * sigf(v);
          v *= al;
          const int rowl = rowl0 + r;
          u16* cl = (rowl < 64) ? &Ast[rowl * 128] : &Bst[(rowl - 64) * 128];
          cl[coll] = f2bfn(v);
        }
      }
    }
    __syncthreads();
#pragma unroll
    for (int vv = 0; vv < 8; ++vv) {
      const int e = t + 256 * vv;
      const int rowl = e >> 4;
      const int col = (e & 15) * 8;
      const u16* cl = (rowl < 64) ? &Ast[rowl * 128] : &Bst[(rowl - 64) * 128];
      const u16x8 val = *(const u16x8*)&cl[col];
      *(u16x8*)&Cb[(size_t)(m0 + rowl) * ldc + n0 + col] = val;
    }
    return;
  }

#pragma unroll
  for (int j = 0; j < 4; ++j) {
    const int col = n0 + wx * 64 + j * 16 + lc;
    const float bj = bias ? bias[col] : 0.f;
    const float al = (col < qn) ? alpha : 1.f;
    const bool vtc = vtblk && (col >= vt0);
#pragma unroll
    for (int i = 0; i < 4; ++i) {
      const int row0 = m0 + wy * 64 + i * 16 + lq * 4;
      float v4[4];
#pragma unroll
      for (int r = 0; r < 4; ++r) {
        float v = acc[i][j][r] + bj;
        if (act) v = v * sigf(v);
        v *= al;
        if (res) v += res[(size_t)(row0 + r) * ldc + col];
        v4[r] = v;
      }
      if (vtc) {
        const int cm = col - vt0;
        const int hh = cm >> 6, dd = cm & 63;
        const int bb = row0 >> 10, nl = row0 & 1023;
        ushort4 o4 = {f2bfn(v4[0]), f2bfn(v4[1]), f2bfn(v4[2]), f2bfn(v4[3])};
        *(ushort4*)&VTout[((size_t)((bb * 8 + hh) * 64 + dd)) * 1024 + nl] = o4;
      } else {
#pragma unroll
        for (int r = 0; r < 4; ++r) {
          const size_t off = (size_t)(row0 + r) * ldc + col;
          if (Cf) Cf[off] = v4[r];
          else Cb[off] = f2bfn(v4[r]);
        }
      }
    }
  }
}

// ---------------------------------------------------------------- flash attention (MFMA)
// q64 tile, 4 waves; merged in-place SP buffer; Q pre-scaled by 0.125*log2e;
// streaming softmax (bounded scores), deferred denominator reduce.
// K/V staged with global_load_lds into stride-64 double buffers with a
// 16B-block XOR source-side swizzle; one barrier per tile. SP is wave-local.
// setprio(1) around MFMA clusters; sliding rel window (tile jt+1's rfr[4]
// == tile jt's rfr[0]) -> 8 instead of 10 rel gathers per tile.
// XCD swizzle: all 16 q-tiles of one (b,h) on one XCD (lin&127 = hb).
__global__ __launch_bounds__(256) void attn_mfma(const u16* __restrict__ QKV,
    const u16* __restrict__ Vt, const u16* __restrict__ Rb, u16* __restrict__ O) {
  const int lin = blockIdx.x;
  const int hb = lin & 127;            // (b,h) group
  const int n0 = (lin >> 7) * 64;      // q-tile
  const int h = hb & 7, b = hb >> 3;
  const int t = threadIdx.x;
  const int w = t >> 6;
  const int lc = t & 15, lq = (t >> 4) & 3;

  __shared__ __align__(16) u16 Ks[2][64 * 64];
  __shared__ __align__(16) u16 Vs[2][64 * 64];
  __shared__ __align__(16) u16 SP[64 * 72];   // pos scatter, then exp(S) in place

  bf16x8 qf[2];
  {
    const size_t qrow = (size_t)(b * 1024 + n0 + w * 16 + lc) * 1536 + h * 64;
    qf[0] = *(const bf16x8*)&QKV[qrow + lq * 8];
    qf[1] = *(const bf16x8*)&QKV[qrow + 32 + lq * 8];
  }

  const u16* Kg = QKV + (size_t)b * 1024 * 1536 + 512 + h * 64;  // + j*1536 + c
  const u16* Vg = Vt + (size_t)(b * 8 + h) * 64 * 1024;          // + d*1024 + j

  const int srow = t >> 3;
  const int scb0 = ((t & 7) ^ (srow & 7)) * 8;
  const int srow1 = (t + 256) >> 3;
  const int scb1 = (((t + 256) & 7) ^ (srow1 & 7)) * 8;

  gl_lds16(&Kg[(size_t)srow * 1536 + scb0], &Ks[0][t * 8]);
  gl_lds16(&Vg[(size_t)srow * 1024 + scb0], &Vs[0][t * 8]);
  gl_lds16(&Kg[(size_t)srow1 * 1536 + scb1], &Ks[0][(t + 256) * 8]);
  gl_lds16(&Vg[(size_t)srow1 * 1024 + scb1], &Vs[0][(t + 256) * 8]);

  float l_r[4] = {0.f, 0.f, 0.f, 0.f};
  f32x4 o[4];
#pragma unroll
  for (int dt = 0; dt < 4; ++dt)
#pragma unroll
    for (int r = 0; r < 4; ++r) o[dt][r] = 0.f;

  const int swz0 = (lq ^ (lc & 7)) * 8;        // ks=0 fragment offset
  const int swz1 = ((4 + lq) ^ (lc & 7)) * 8;  // ks=1 fragment offset

  bf16x8 rsave[2];                             // rfr[0] of previous tile

  int buf = 0;
  for (int jt = 0; jt < 16; ++jt) {
    const int j0 = jt * 64;
    __syncthreads();   // waits vmcnt(0): prefetched tile complete; buf^1 free

    if (jt < 15) {
      const int j1 = j0 + 64;
      gl_lds16(&Kg[(size_t)(j1 + srow) * 1536 + scb0], &Ks[buf ^ 1][t * 8]);
      gl_lds16(&Vg[(size_t)srow * 1024 + j1 + scb0], &Vs[buf ^ 1][t * 8]);
      gl_lds16(&Kg[(size_t)(j1 + srow1) * 1536 + scb1], &Ks[buf ^ 1][(t + 256) * 8]);
      gl_lds16(&Vg[(size_t)srow1 * 1024 + j1 + scb1], &Vs[buf ^ 1][(t + 256) * 8]);
    }

    f32x4 qk[4], pa[5];
#pragma unroll
    for (int j = 0; j < 4; ++j)
#pragma unroll
      for (int r = 0; r < 4; ++r) qk[j][r] = 0.f;
#pragma unroll
    for (int rtl = 0; rtl < 5; ++rtl)
#pragma unroll
      for (int r = 0; r < 4; ++r) pa[rtl][r] = 0.f;

    const int base = n0 - j0 - 63;
    const u16* rp[4];
#pragma unroll
    for (int rtl = 0; rtl < 4; ++rtl) {
      int p = base + (w + rtl) * 16 + lc;
      p = (p < -512 ? -512 : (p > 512 ? 512 : p)) + 512;
      rp[rtl] = Rb + (size_t)p * 64 + lq * 8;
    }
    const u16* rp4;
    {
      int p = base + (w + 4) * 16 + lc;
      p = (p < -512 ? -512 : (p > 512 ? 512 : p)) + 512;
      rp4 = Rb + (size_t)p * 64 + lq * 8;
    }

    __builtin_amdgcn_s_setprio(1);
#pragma unroll
    for (int ks = 0; ks < 2; ++ks) {
      const int koff = ks ? swz1 : swz0;
      bf16x8 rfr[4];
#pragma unroll
      for (int rtl = 0; rtl < 4; ++rtl)
        rfr[rtl] = *(const bf16x8*)&rp[rtl][ks * 32];
      const bf16x8 rfr4 = (jt == 0) ? *(const bf16x8*)&rp4[ks * 32] : rsave[ks];
#pragma unroll
      for (int j = 0; j < 4; ++j) {
        const bf16x8 bf = *(const bf16x8*)&Ks[buf][(j * 16 + lc) * 64 + koff];
        qk[j] = __builtin_amdgcn_mfma_f32_16x16x32_bf16(qf[ks], bf, qk[j], 0, 0, 0);
      }
#pragma unroll
      for (int rtl = 0; rtl < 4; ++rtl)
        pa[rtl] = __builtin_amdgcn_mfma_f32_16x16x32_bf16(qf[ks], rfr[rtl], pa[rtl], 0, 0, 0);
      pa[4] = __builtin_amdgcn_mfma_f32_16x16x32_bf16(qf[ks], rfr4, pa[4], 0, 0, 0);
      rsave[ks] = rfr[0];
    }
    __builtin_amdgcn_s_setprio(0);

    // skewed scatter: P[qr][didx] -> SP[qr][jc], jc = qr - didx + 63 (wave-local)
#pragma unroll
    for (int rtl = 0; rtl < 5; ++rtl) {
      const int didx = (w + rtl) * 16 + lc;
#pragma unroll
      for (int r = 0; r < 4; ++r) {
        const int qr = w * 16 + lq * 4 + r;
        const int jc = qr - didx + 63;
        if ((unsigned)jc < 64u) SP[qr * 72 + jc] = f2bfn(pa[rtl][r]);
      }
    }

    // streaming softmax in place
#pragma unroll
    for (int r = 0; r < 4; ++r) {
      const int qr = w * 16 + lq * 4 + r;
#pragma unroll
      for (int ti = 0; ti < 4; ++ti) {
        const int a = qr * 72 + ti * 16 + lc;
        const float e = exp2f(qk[ti][r] + bf2f(SP[a]));
        SP[a] = f2bfn(e);
        l_r[r] += e;
      }
    }

    // PV
    __builtin_amdgcn_s_setprio(1);
#pragma unroll
    for (int ks = 0; ks < 2; ++ks) {
      const bf16x8 af = *(const bf16x8*)&SP[(w * 16 + lc) * 72 + ks * 32 + lq * 8];
      const int koff = ks ? swz1 : swz0;
#pragma unroll
      for (int dt = 0; dt < 4; ++dt) {
        const bf16x8 bf = *(const bf16x8*)&Vs[buf][(dt * 16 + lc) * 64 + koff];
        o[dt] = __builtin_amdgcn_mfma_f32_16x16x32_bf16(af, bf, o[dt], 0, 0, 0);
      }
    }
    __builtin_amdgcn_s_setprio(0);
    buf ^= 1;
  }

#pragma unroll
  for (int r = 0; r < 4; ++r) {
#pragma unroll
    for (int msk = 1; msk < 16; msk <<= 1) l_r[r] += __shfl_xor(l_r[r], msk);
  }

#pragma unroll
  for (int r = 0; r < 4; ++r) {
    const float inv = 1.f / l_r[r];
    const size_t row = (size_t)(b * 1024 + n0 + w * 16 + lq * 4 + r);
#pragma unroll
    for (int dt = 0; dt < 4; ++dt)
      O[row * 512 + h * 64 + dt * 16 + lc] = f2bfn(o[dt][r] * inv);
  }
}

// ---------------------------------------------------------------- depthwise conv (GLU fused)
// in = HID (2048 cols): h = a*sig(g) computed in the hs-fill loop.
// Fill vectorized — ushort4 loads (8B), float4 LDS stores.
__global__ __launch_bounds__(256) void dwconv_kernel(const u16* __restrict__ in,
    const float* __restrict__ w, const float* __restrict__ bias,
    u16* __restrict__ out) {
  const int n0 = blockIdx.x * 64;
  const int c0 = blockIdx.y * 64;
  const int b = blockIdx.z;
  const int t = threadIdx.x;
  __shared__ float hs[94][64];
  __shared__ float wsh[31][64];
  const int c = t & 63;
  const int g = t >> 6;
  {
    const int cg = (t & 15) * 4;   // 4 consecutive cols
    const int rg = t >> 4;         // 16 row groups
    for (int r = rg; r < 94; r += 16) {
      const int n = n0 - 30 + r;
      float4 v4 = {0.f, 0.f, 0.f, 0.f};
      if (n >= 0) {
        const size_t rowb = (size_t)(b * 1024 + n) * 2048;
        const ushort4 a4 = *(const ushort4*)&in[rowb + c0 + cg];
        const ushort4 g4 = *(const ushort4*)&in[rowb + 1024 + c0 + cg];
        v4.x = bf2f(a4.x) * sigf(bf2f(g4.x));
        v4.y = bf2f(a4.y) * sigf(bf2f(g4.y));
        v4.z = bf2f(a4.z) * sigf(bf2f(g4.z));
        v4.w = bf2f(a4.w) * sigf(bf2f(g4.w));
      }
      *(float4*)&hs[r][cg] = v4;
    }
  }
  for (int idx = t; idx < 31 * 64; idx += 256) {
    const int tap = idx >> 6, cc = idx & 63;
    wsh[tap][cc] = w[(size_t)(c0 + cc) * 31 + tap];
  }
  __syncthreads();
  float wr[31];
#pragma unroll
  for (int k = 0; k < 31; ++k) wr[k] = wsh[k][c];
  const float bsv = bias[c0 + c];
  float win[46];
  const int rbase = g * 16;
#pragma unroll
  for (int k = 0; k < 46; ++k) win[k] = hs[rbase + k][c];
#pragma unroll
  for (int i = 0; i < 16; ++i) {
    float acc = bsv;
#pragma unroll
    for (int k = 0; k < 31; ++k) acc += wr[k] * win[i + k];
    acc = acc * sigf(acc);
    out[(size_t)(b * 1024 + n0 + rbase + i) * 1024 + c0 + c] = f2bfn(acc);
  }
}

// ---------------------------------------------------------------- launch
extern "C" void kernel_launch(void* const* d_in, const int* in_sizes, int n_in,
                              void* d_out, int out_size, void* d_ws, size_t ws_size,
                              hipStream_t stream) {
  const float* x        = (const float*)d_in[0];
  const float* ff1_ln_g = (const float*)d_in[1];
  const float* ff1_ln_b = (const float*)d_in[2];
  const float* ff1_w1   = (const float*)d_in[3];
  const float* ff1_b1   = (const float*)d_in[4];
  const float* ff1_w2   = (const float*)d_in[5];
  const float* ff1_b2   = (const float*)d_in[6];
  const float* attn_ln_g= (const float*)d_in[7];
  const float* attn_ln_b= (const float*)d_in[8];
  const float* wq       = (const float*)d_in[9];
  const float* wkv      = (const float*)d_in[10];
  const float* wo       = (const float*)d_in[11];
  const float* bo       = (const float*)d_in[12];
  const float* rel_emb  = (const float*)d_in[13];
  const float* conv_ln_g= (const float*)d_in[14];
  const float* conv_ln_b= (const float*)d_in[15];
  const float* conv1_w  = (const float*)d_in[16];
  const float* conv1_b  = (const float*)d_in[17];
  const float* dw_w     = (const float*)d_in[18];
  const float* dw_b     = (const float*)d_in[19];
  const float* conv2_w  = (const float*)d_in[20];
  const float* conv2_b  = (const float*)d_in[21];
  const float* ff2_ln_g = (const float*)d_in[22];
  const float* ff2_ln_b = (const float*)d_in[23];
  const float* ff2_w1   = (const float*)d_in[24];
  const float* ff2_b1   = (const float*)d_in[25];
  const float* ff2_w2   = (const float*)d_in[26];
  const float* ff2_b2   = (const float*)d_in[27];
  const float* post_ln_g= (const float*)d_in[28];
  const float* post_ln_b= (const float*)d_in[29];

  float* XRES = (float*)d_out;
  u16* ws = (u16*)d_ws;
  u16* LNB  = ws;                                // BN*512
  u16* HID  = LNB + (size_t)BN * 512;            // BN*2048
  u16* QKVB = HID + (size_t)BN * 2048;           // BN*1536
  u16* VT   = QKVB + (size_t)BN * 1536;          // 8192*1024
  u16* DWB  = QKVB;                              // alias (QKV dead after attn)
  u16* WTp = VT + (size_t)8192 * 1024;
  u16* wt_ff1w1 = WTp;                 WTp += (size_t)2048 * 512;
  u16* wt_ff1w2 = WTp;                 WTp += (size_t)512 * 2048;
  u16* wt_qkv   = WTp;                 WTp += (size_t)1536 * 512;
  u16* wt_wo    = WTp;                 WTp += (size_t)512 * 512;
  u16* wt_conv1 = WTp;                 WTp += (size_t)2048 * 512;
  u16* wt_conv2 = WTp;                 WTp += (size_t)512 * 1024;
  u16* wt_ff2w1 = WTp;                 WTp += (size_t)2048 * 512;
  u16* wt_ff2w2 = WTp;                 WTp += (size_t)512 * 2048;
  u16* RELB     = WTp;

  const dim3 blk(256);
  const float SC = 0.125f * 1.44269504f;  // folded into Q projection

  // weight prep
  wtrans<<<dim3(64, 16), blk, 0, stream>>>(ff1_w1, wt_ff1w1, 512, 2048);
  wtrans<<<dim3(16, 64), blk, 0, stream>>>(ff1_w2, wt_ff1w2, 2048, 512);
  wtrans<<<dim3(16, 16), blk, 0, stream>>>(wq, wt_qkv, 512, 512);
  wtrans<<<dim3(32, 16), blk, 0, stream>>>(wkv, wt_qkv + (size_t)512 * 512, 512, 1024);
  wtrans<<<dim3(16, 16), blk, 0, stream>>>(wo, wt_wo, 512, 512);
  wtrans<<<dim3(64, 16), blk, 0, stream>>>(conv1_w, wt_conv1, 512, 2048);
  wtrans<<<dim3(16, 32), blk, 0, stream>>>(conv2_w, wt_conv2, 1024, 512);
  wtrans<<<dim3(64, 16), blk, 0, stream>>>(ff2_w1, wt_ff2w1, 512, 2048);
  wtrans<<<dim3(16, 64), blk, 0, stream>>>(ff2_w2, wt_ff2w2, 2048, 512);
  cvt_bf16<<<257, blk, 0, stream>>>(rel_emb, RELB, 1025 * 64);

  // --- FF1 (half-step)
  ln_kernel<<<BN / 2, blk, 0, stream>>>(x, ff1_ln_g, ff1_ln_b, LNB, nullptr);
  gemm256<<<dim3(8, 64), dim3(512), 0, stream>>>(LNB, wt_ff1w1, ff1_b1, HID, 512, 2048, 1);
  gemm_bf16<<<dim3(4, 128), blk, 0, stream>>>(HID, wt_ff1w2, ff1_b2, x,
                                              XRES, nullptr, nullptr, 2048, 512, 512, 0.5f, 0, 512, 0);

  // --- attention (merged QKV projection: Q cols scaled by SC, V cols >=1024
  //     written transposed into VT; K row-major)
  ln_kernel<<<BN / 2, blk, 0, stream>>>(XRES, attn_ln_g, attn_ln_b, LNB, nullptr);
  gemm_bf16<<<dim3(12, 128), blk, 0, stream>>>(LNB, wt_qkv, nullptr, nullptr,
                                               nullptr, QKVB, VT, 512, 1536, 1536, SC, 0, 512, 1024);
  attn_mfma<<<dim3(2048), blk, 0, stream>>>(QKVB, VT, RELB, LNB);
  gemm_bf16<<<dim3(4, 128), blk, 0, stream>>>(LNB, wt_wo, bo, XRES,
                                              XRES, nullptr, nullptr, 512, 512, 512, 1.f, 0, 512, 0);

  // --- conv module (GLU fused into dwconv; HID -> DWB directly)
  ln_kernel<<<BN / 2, blk, 0, stream>>>(XRES, conv_ln_g, conv_ln_b, LNB, nullptr);
  gemm256<<<dim3(8, 64), dim3(512), 0, stream>>>(LNB, wt_conv1, conv1_b, HID, 512, 2048, 0);
  dwconv_kernel<<<dim3(16, 16, 16), blk, 0, stream>>>(HID, dw_w, dw_b, DWB);
  gemm_bf16<<<dim3(4, 128), blk, 0, stream>>>(DWB, wt_conv2, conv2_b, XRES,
                                              XRES, nullptr, nullptr, 1024, 512, 512, 1.f, 0, 512, 0);

  // --- FF2 (half-step)
  ln_kernel<<<BN / 2, blk, 0, stream>>>(XRES, ff2_ln_g, ff2_ln_b, LNB, nullptr);
  gemm256<<<dim3(8, 64), dim3(512), 0, stream>>>(LNB, wt_ff2w1, ff2_b1, HID, 512, 2048, 1);
  gemm_bf16<<<dim3(4, 128), blk, 0, stream>>>(HID, wt_ff2w2, ff2_b2, XRES,
                                              XRES, nullptr, nullptr, 2048, 512, 512, 0.5f, 0, 512, 0);

  // --- final layernorm
  ln_kernel<<<BN / 2, blk, 0, stream>>>(XRES, post_ln_g, post_ln_b, nullptr, XRES);
}